// Round 5
// baseline (151.726 us; speedup 1.0000x reference)
//
#include <hip/hip_runtime.h>

typedef unsigned short u16;
typedef __attribute__((ext_vector_type(8))) u16    u16x8;
typedef __attribute__((ext_vector_type(4))) u16    u16x4;
typedef __attribute__((ext_vector_type(2))) unsigned u32x2;
typedef __attribute__((ext_vector_type(8))) __bf16 bf16x8;
typedef __attribute__((ext_vector_type(4))) float  f32x4;
typedef __attribute__((ext_vector_type(16))) float f32x16;

__device__ __forceinline__ u16 f2bf(float f) {
    unsigned u = __float_as_uint(f);
    u += 0x7fffu + ((u >> 16) & 1u);   // RNE
    return (u16)(u >> 16);
}
__device__ __forceinline__ bf16x8 ldbf8(const u16* p) {
    return __builtin_bit_cast(bf16x8, *(const u16x8*)p);
}
__device__ __forceinline__ f32x4 mfma16(bf16x8 a, bf16x8 b, f32x4 c) {
    return __builtin_amdgcn_mfma_f32_16x16x32_bf16(a, b, c, 0, 0, 0);
}
__device__ __forceinline__ f32x16 mfma32x(bf16x8 a, bf16x8 b, f32x16 c) {
    return __builtin_amdgcn_mfma_f32_32x32x16_bf16(a, b, c, 0, 0, 0);
}
__device__ __forceinline__ float exp2a(float x) {
    float r; asm("v_exp_f32 %0, %1" : "=v"(r) : "v"(x)); return r;
}
__device__ __forceinline__ unsigned cvtpk(float lo, float hiv) {
    unsigned r; asm("v_cvt_pk_bf16_f32 %0, %1, %2" : "=v"(r) : "v"(lo), "v"(hiv)); return r;
}
__device__ __forceinline__ u32x2 permswap2(unsigned a, unsigned b) {
    return __builtin_amdgcn_permlane32_swap(a, b, false, false);
}
__device__ __forceinline__ float combine_sum(float x) {   // x + partner-half x (orientation-robust)
    u32x2 pr = permswap2(__float_as_uint(x), __float_as_uint(x));
    return __uint_as_float(pr[0]) + __uint_as_float(pr[1]);
}
__device__ __forceinline__ bf16x8 pack4(unsigned a, unsigned b, unsigned c, unsigned d) {
    union { unsigned u[4]; bf16x8 v; } t; t.u[0] = a; t.u[1] = b; t.u[2] = c; t.u[3] = d; return t.v;
}

// ---------------- weight transpose + cast:  Wt[n][k] = bf16(W[k][n] * scale) ----------------
__global__ void transpose_cast(const float* __restrict__ W, u16* __restrict__ Wt, int K, int N, float scale) {
    __shared__ float tile[32][33];
    int kb = blockIdx.x * 32, nb = blockIdx.y * 32;
    int tx = threadIdx.x, ty = threadIdx.y;          // (32, 8)
#pragma unroll
    for (int i = 0; i < 32; i += 8)
        tile[ty + i][tx] = W[(size_t)(kb + ty + i) * N + nb + tx];
    __syncthreads();
#pragma unroll
    for (int i = 0; i < 32; i += 8)
        Wt[(size_t)(nb + ty + i) * K + kb + tx] = f2bf(tile[tx][ty + i] * scale);
}

// ---------------- LayerNorm + cast: xn = bf16(LN(x)*gamma), xb = bf16(x) ----------------
__global__ __launch_bounds__(256) void ln_cast(const float* __restrict__ x, const float* __restrict__ gamma,
                                               u16* __restrict__ xn, u16* __restrict__ xb) {
    const int row = blockIdx.x;          // 4096 rows of 1024
    const int t = threadIdx.x;           // 256 threads, 4 floats each
    const float4 v = ((const float4*)(x + (size_t)row * 1024))[t];
    float s  = v.x + v.y + v.z + v.w;
    float s2 = v.x * v.x + v.y * v.y + v.z * v.z + v.w * v.w;
#pragma unroll
    for (int off = 32; off; off >>= 1) { s += __shfl_down(s, off); s2 += __shfl_down(s2, off); }
    __shared__ float red[2][4];
    const int w = t >> 6, lane = t & 63;
    if (lane == 0) { red[0][w] = s; red[1][w] = s2; }
    __syncthreads();
    s  = red[0][0] + red[0][1] + red[0][2] + red[0][3];
    s2 = red[1][0] + red[1][1] + red[1][2] + red[1][3];
    const float mu  = s * (1.0f / 1024.0f);
    const float var = s2 * (1.0f / 1024.0f) - mu * mu;
    const float rs  = rsqrtf(var + 1e-5f);
    const float4 g = ((const float4*)gamma)[t];
    u16x4 on, ob;
    on.x = f2bf((v.x - mu) * rs * g.x); on.y = f2bf((v.y - mu) * rs * g.y);
    on.z = f2bf((v.z - mu) * rs * g.z); on.w = f2bf((v.w - mu) * rs * g.w);
    ob.x = f2bf(v.x); ob.y = f2bf(v.y); ob.z = f2bf(v.z); ob.w = f2bf(v.w);
    ((u16x4*)(xn + (size_t)row * 1024))[t] = on;
    ((u16x4*)(xb + (size_t)row * 1024))[t] = ob;
}

// ---------------- GEMM: C[M,N] = A[M,K] @ Bt[N,K]^T (bf16 in, f32 acc) ----------------
template<int BM, int BN, int EPI>
__global__ __launch_bounds__(256) void gemm_bt(const u16* __restrict__ A, const u16* __restrict__ Bt,
                                               u16* __restrict__ Cb, float* __restrict__ Cf,
                                               u16* __restrict__ Cv, int M, int N, int K) {
    constexpr int WM = BM / 2, WN = BN / 2, FM = WM / 16, FN = WN / 16;
    constexpr int CHA = BM * 4, CH = (BM + BN) * 4, ITERS = CH / 256;  // 16B chunks, BK=32
    __shared__ __align__(16) u16 lds[2][(BM + BN) * 32];
    const int tid = threadIdx.x;
    const int m0 = blockIdx.x * BM, n0 = blockIdx.y * BN;
    const int w = tid >> 6, lane = tid & 63, cl = lane & 15, kg = lane >> 4;
    const int wr = w >> 1, wc = w & 1;

    auto stage = [&](int buf, int k0) {
#pragma unroll
        for (int it = 0; it < ITERS; ++it) {
            int c = it * 256 + tid;
            const u16* g;
            if (c < CHA) { int r = c >> 2, cc = c & 3; g = A  + (size_t)(m0 + r) * K + k0 + cc * 8; }
            else { int c2 = c - CHA; int r = c2 >> 2, cc = c2 & 3; g = Bt + (size_t)(n0 + r) * K + k0 + cc * 8; }
            __builtin_amdgcn_global_load_lds(
                (const __attribute__((address_space(1))) unsigned int*)g,
                (__attribute__((address_space(3))) unsigned int*)&lds[buf][c * 8], 16, 0, 0);
        }
    };

    const f32x4 zero = {0.f, 0.f, 0.f, 0.f};
    f32x4 acc[FM][FN];
#pragma unroll
    for (int m = 0; m < FM; m++)
#pragma unroll
        for (int n = 0; n < FN; n++) acc[m][n] = zero;

    const int KT = K / 32;
    stage(0, 0);
    for (int t = 0; t < KT; ++t) {
        __syncthreads();
        if (t + 1 < KT) stage((t + 1) & 1, (t + 1) * 32);
        const u16* As = &lds[t & 1][0];
        const u16* Bs = &lds[t & 1][BM * 32];
        bf16x8 af[FM], bfr[FN];
#pragma unroll
        for (int m = 0; m < FM; m++) af[m]  = ldbf8(As + (wr * WM + m * 16 + cl) * 32 + kg * 8);
#pragma unroll
        for (int n = 0; n < FN; n++) bfr[n] = ldbf8(Bs + (wc * WN + n * 16 + cl) * 32 + kg * 8);
#pragma unroll
        for (int m = 0; m < FM; m++)
#pragma unroll
            for (int n = 0; n < FN; n++) acc[m][n] = mfma16(af[m], bfr[n], acc[m][n]);
    }

#pragma unroll
    for (int m = 0; m < FM; m++)
#pragma unroll
        for (int n = 0; n < FN; n++)
#pragma unroll
            for (int r = 0; r < 4; r++) {
                const int row = m0 + wr * WM + m * 16 + kg * 4 + r;
                const int col = n0 + wc * WN + n * 16 + cl;
                const float v = acc[m][n][r];
                if constexpr (EPI == 0) Cb[(size_t)row * N + col] = f2bf(v);
                else if constexpr (EPI == 1) Cf[(size_t)row * N + col] = v;
                else {
                    if (col < 64) Cb[(size_t)row * 64 + col] = f2bf(v);
                    else { int bb = row >> 11, s = row & 2047;
                           Cv[((size_t)bb * 64 + (col - 64)) * 2048 + s] = f2bf(v); }
                }
            }
}

// ---------------- kmax: kmaxv[b] = max_row ||k_row||_2 ----------------
__global__ __launch_bounds__(256) void kmax_kernel(const u16* __restrict__ kb, float* __restrict__ kmaxv) {
    const int b = blockIdx.x, tid = threadIdx.x;
    float mx = 0.f;
    for (int r = tid; r < 2048; r += 256) {
        const u16* kp = kb + ((size_t)b * 2048 + r) * 64;
        float s2 = 0.f;
#pragma unroll
        for (int i = 0; i < 8; i++) {
            u16x8 v = ((const u16x8*)kp)[i];
#pragma unroll
            for (int j = 0; j < 8; j++) {
                const float f = __uint_as_float(((unsigned)v[j]) << 16);
                s2 = fmaf(f, f, s2);
            }
        }
        mx = fmaxf(mx, s2);
    }
#pragma unroll
    for (int off = 32; off; off >>= 1) mx = fmaxf(mx, __shfl_down(mx, off));
    __shared__ float red[4];
    if ((tid & 63) == 0) red[tid >> 6] = mx;
    __syncthreads();
    if (tid == 0) kmaxv[b] = sqrtf(fmaxf(fmaxf(red[0], red[1]), fmaxf(red[2], red[3])));
}

// ---------------- causal flash attention, MQA, Dh=64, fixed-bound softmax ----------------
// m_i = ||q_i||*kmax_b >= max_j s_ij (Cauchy-Schwarz, exact for the bf16 values in MFMA).
// No online max/rescale: P = exp2(s - m_i); l accumulates per-lane; merge = plain add.
// Block = one (b,h,q-tile); 4 waves split kv tiles jt ≡ w (mod 4); LDS add-merge at end.
__global__ __launch_bounds__(256) void attn_fwd(const u16* __restrict__ q, const u16* __restrict__ k,
                                                const u16* __restrict__ vt, const float* __restrict__ kmaxv,
                                                u16* __restrict__ o) {
    constexpr int S = 2048;
    const int bid = blockIdx.x;                  // tt*32 + bh : big-t first
    const int bh = bid & 31, t = 63 - (bid >> 5);
    const int h = bh & 15, b = bh >> 4;
    const int tid = threadIdx.x, w = tid >> 6, lane = tid & 63;
    const int l31 = lane & 31;
    const bool hi = (lane & 32) != 0;
    const int hi8 = hi ? 8 : 0;
    const int q0 = t * 32;
    const size_t bS = (size_t)b * S;

    __shared__ __align__(16) float mrg[3][64][36];   // stride 36 f32 = 144B (16B aligned)

    bf16x8 qf[4];                                // Q B-frags: col=q=l31, k=hi*8+j (+16*sub)
    {
        const u16* qp = q + (bS + q0 + l31) * 1024 + h * 64 + hi8;
#pragma unroll
        for (int sub = 0; sub < 4; sub++) qf[sub] = ldbf8(qp + sub * 16);
    }
    // per-row softmax bound: m = ||q_row|| * kmax_b (q already has SCALE*log2e folded)
    float qn2 = 0.f;
#pragma unroll
    for (int sub = 0; sub < 4; sub++) {
        const u16x8 uv = __builtin_bit_cast(u16x8, qf[sub]);
#pragma unroll
        for (int j = 0; j < 8; j++) {
            const float v = __uint_as_float(((unsigned)uv[j]) << 16);
            qn2 = fmaf(v, v, qn2);
        }
    }
    qn2 = combine_sum(qn2);
    const float mB = sqrtf(qn2) * kmaxv[b];

    f32x16 accO0, accO1;                         // O^T d-tiles: col=q=l31, row(r,hi)=d
#pragma unroll
    for (int r = 0; r < 16; r++) { accO0[r] = 0.f; accO1[r] = 0.f; }
    float l_run = 0.f;

    auto loadK = [&](int jt, bf16x8 (&kf)[4]) {
        const u16* kp = k + (bS + jt * 32 + l31) * 64 + hi8;
#pragma unroll
        for (int sub = 0; sub < 4; sub++) kf[sub] = ldbf8(kp + sub * 16);
    };

    auto body = [&](int jt, bf16x8 (&kf)[4], bf16x8 (&kfn)[4]) {
        f32x16 s;
#pragma unroll
        for (int r = 0; r < 16; r++) s[r] = 0.f;
#pragma unroll
        for (int sub = 0; sub < 4; sub++) s = mfma32x(kf[sub], qf[sub], s);
        bf16x8 vf00, vf01, vf10, vf11;           // V^T A-frags: row=d, k=kv (load early)
        {
            const u16* vp = vt + ((size_t)b * 64 + l31) * S + jt * 32 + hi8;
            vf00 = ldbf8(vp);            vf01 = ldbf8(vp + 16);
            vf10 = ldbf8(vp + 32 * S);   vf11 = ldbf8(vp + 32 * S + 16);
        }
        if (jt + 4 <= t) loadK(jt + 4, kfn);     // prefetch this wave's next K
        if (jt == t) {                           // diagonal tile: causal mask
#pragma unroll
            for (int r = 0; r < 16; r++) {
                const int kvl = (r & 3) + 8 * (r >> 2) + (hi ? 4 : 0);
                if (kvl > l31) s[r] = -1e30f;
            }
        }
        // P = exp2(s - m); per-lane partial l (cross-half combine deferred to end)
        float p0 = 0.f, p1 = 0.f;
#pragma unroll
        for (int r = 0; r < 16; r += 2) {
            const float ea = exp2a(s[r] - mB);
            const float eb = exp2a(s[r + 1] - mB);
            s[r] = ea; s[r + 1] = eb;
            p0 += ea; p1 += eb;
        }
        l_run += p0 + p1;
        // P -> bf16 B-frags via 2 permlane per 16-kv half (T12 cheap form)
        unsigned w0 = cvtpk(s[0], s[1]),  w1 = cvtpk(s[2], s[3]);
        unsigned w2 = cvtpk(s[4], s[5]),  w3 = cvtpk(s[6], s[7]);
        u32x2 r02 = permswap2(w0, w2), r13 = permswap2(w1, w3);
        bf16x8 pf0 = pack4(r02[0], r13[0], r02[1], r13[1]);
        unsigned y0 = cvtpk(s[8], s[9]),   y1 = cvtpk(s[10], s[11]);
        unsigned y2 = cvtpk(s[12], s[13]), y3 = cvtpk(s[14], s[15]);
        u32x2 t02 = permswap2(y0, y2), t13 = permswap2(y1, y3);
        bf16x8 pf1 = pack4(t02[0], t13[0], t02[1], t13[1]);
        accO0 = mfma32x(vf00, pf0, accO0);
        accO0 = mfma32x(vf01, pf1, accO0);
        accO1 = mfma32x(vf10, pf0, accO1);
        accO1 = mfma32x(vf11, pf1, accO1);
    };

    bf16x8 kA[4], kB[4];
    if (w <= t) loadK(w, kA);
    for (int jt = w; jt <= t; jt += 8) {
        body(jt, kA, kB);
        if (jt + 4 <= t) body(jt + 4, kB, kA);
    }
    float l_tot = combine_sum(l_run);            // full row sum for this wave's kv tiles

    // ---- add-merge (fixed m -> no rescaling needed) ----
    if (w > 0) {
        float* p = &mrg[w - 1][lane][0];
        *(f32x16*)p        = accO0;
        *(f32x16*)(p + 16) = accO1;
        p[32] = l_tot;
    }
    __syncthreads();
    if (w == 0) {
#pragma unroll
        for (int bi = 0; bi < 3; bi++) {
            const float* p = &mrg[bi][lane][0];
            const f32x16 a0 = *(const f32x16*)p;
            const f32x16 a1 = *(const f32x16*)(p + 16);
#pragma unroll
            for (int r = 0; r < 16; r++) { accO0[r] += a0[r]; accO1[r] += a1[r]; }
            l_tot += p[32];
        }
        // epilogue: O^T -> LDS [32q][72] (aliases mrg) -> coalesced global
        const float rl = 1.0f / l_tot;
        u16* lb = (u16*)&mrg[0][0][0];
        asm volatile("s_waitcnt lgkmcnt(0)" ::: "memory");
#pragma unroll
        for (int i = 0; i < 8; i++) {
            const int d = ((2 * i) & 3) + 8 * ((2 * i) >> 2) + (hi ? 4 : 0);
            *(unsigned*)&lb[l31 * 72 + d]      = cvtpk(accO0[2 * i] * rl, accO0[2 * i + 1] * rl);
            *(unsigned*)&lb[l31 * 72 + 32 + d] = cvtpk(accO1[2 * i] * rl, accO1[2 * i + 1] * rl);
        }
        asm volatile("s_waitcnt lgkmcnt(0)" ::: "memory");
#pragma unroll
        for (int i = 0; i < 4; i++) {
            const int qq = i * 8 + (lane >> 3), dd = (lane & 7) * 8;
            *(u16x8*)(o + (bS + q0 + qq) * 1024 + h * 64 + dd) = *(const u16x8*)&lb[qq * 72 + dd];
        }
    }
}

// ---------------- launcher ----------------
extern "C" void kernel_launch(void* const* d_in, const int* in_sizes, int n_in,
                              void* d_out, int out_size, void* d_ws, size_t ws_size,
                              hipStream_t stream) {
    const float* x     = (const float*)d_in[0];
    const float* gamma = (const float*)d_in[1];
    const float* Wq    = (const float*)d_in[2];
    const float* Wkv   = (const float*)d_in[3];
    const float* Wo    = (const float*)d_in[4];
    float* out = (float*)d_out;
    char* ws = (char*)d_ws;

    u16* Wq_t  = (u16*)(ws + 0);             // 2 MB
    u16* Wo_t  = (u16*)(ws + (2u << 20));    // 2 MB
    u16* Wkv_t = (u16*)(ws + (4u << 20));    // 256 KB
    u16* xn    = (u16*)(ws + 4456448u);      // 8 MB
    u16* xb    = (u16*)(ws + 12845056u);     // 8 MB (free after kv-gemm; reused for kmaxv)
    u16* qb    = (u16*)(ws + 21233664u);     // 8 MB
    u16* kb    = (u16*)(ws + 29622272u);     // 512 KB
    u16* vtb   = (u16*)(ws + 30146560u);     // 512 KB
    u16* attb  = (u16*)(ws + 30670848u);     // 8 MB
    float* kmaxv = (float*)xb;               // 8 B, written after xb's last use

    const dim3 tb(32, 8);
    const float qscale = 0.125f * 1.44269504f;   // SCALE * log2(e) folded into Wq
    transpose_cast<<<dim3(32, 32), tb, 0, stream>>>(Wq,  Wq_t,  1024, 1024, qscale);
    transpose_cast<<<dim3(32, 4),  tb, 0, stream>>>(Wkv, Wkv_t, 1024, 128, 1.0f);
    transpose_cast<<<dim3(32, 32), tb, 0, stream>>>(Wo,  Wo_t,  1024, 1024, 1.0f);

    ln_cast<<<4096, 256, 0, stream>>>(x, gamma, xn, xb);

    gemm_bt<128, 128, 0><<<dim3(32, 8), 256, 0, stream>>>(xn, Wq_t, qb, nullptr, nullptr, 4096, 1024, 1024);
    gemm_bt<64, 64, 2><<<dim3(64, 2), 256, 0, stream>>>(xb, Wkv_t, kb, nullptr, vtb, 4096, 128, 1024);
    kmax_kernel<<<2, 256, 0, stream>>>(kb, kmaxv);
    attn_fwd<<<2048, 256, 0, stream>>>(qb, kb, vtb, kmaxv, attb);
    gemm_bt<128, 128, 1><<<dim3(32, 8), 256, 0, stream>>>(attb, Wo_t, nullptr, out, nullptr, 4096, 1024, 1024);
}

// Round 6
// 118.597 us; speedup vs baseline: 1.2793x; 1.2793x over previous
//
#include <hip/hip_runtime.h>

typedef unsigned short u16;
typedef __attribute__((ext_vector_type(8))) u16    u16x8;
typedef __attribute__((ext_vector_type(4))) u16    u16x4;
typedef __attribute__((ext_vector_type(2))) unsigned u32x2;
typedef __attribute__((ext_vector_type(8))) __bf16 bf16x8;
typedef __attribute__((ext_vector_type(4))) float  f32x4;
typedef __attribute__((ext_vector_type(16))) float f32x16;

__device__ __forceinline__ u16 f2bf(float f) {
    unsigned u = __float_as_uint(f);
    u += 0x7fffu + ((u >> 16) & 1u);   // RNE
    return (u16)(u >> 16);
}
__device__ __forceinline__ bf16x8 ldbf8(const u16* p) {
    return __builtin_bit_cast(bf16x8, *(const u16x8*)p);
}
__device__ __forceinline__ f32x4 mfma16(bf16x8 a, bf16x8 b, f32x4 c) {
    return __builtin_amdgcn_mfma_f32_16x16x32_bf16(a, b, c, 0, 0, 0);
}
__device__ __forceinline__ f32x16 mfma32x(bf16x8 a, bf16x8 b, f32x16 c) {
    return __builtin_amdgcn_mfma_f32_32x32x16_bf16(a, b, c, 0, 0, 0);
}
__device__ __forceinline__ float exp2a(float x) {
    float r; asm("v_exp_f32 %0, %1" : "=v"(r) : "v"(x)); return r;
}
__device__ __forceinline__ unsigned cvtpk(float lo, float hiv) {
    unsigned r; asm("v_cvt_pk_bf16_f32 %0, %1, %2" : "=v"(r) : "v"(lo), "v"(hiv)); return r;
}
__device__ __forceinline__ u32x2 permswap2(unsigned a, unsigned b) {
    return __builtin_amdgcn_permlane32_swap(a, b, false, false);
}
__device__ __forceinline__ float combine_sum(float x) {   // x + partner-half x (orientation-robust)
    u32x2 pr = permswap2(__float_as_uint(x), __float_as_uint(x));
    return __uint_as_float(pr[0]) + __uint_as_float(pr[1]);
}
__device__ __forceinline__ bf16x8 pack4(unsigned a, unsigned b, unsigned c, unsigned d) {
    union { unsigned u[4]; bf16x8 v; } t; t.u[0] = a; t.u[1] = b; t.u[2] = c; t.u[3] = d; return t.v;
}

// ---------------- weight transpose + cast:  Wt[n][k] = bf16(W[k][n] * scale) ----------------
__global__ void transpose_cast(const float* __restrict__ W, u16* __restrict__ Wt, int K, int N, float scale) {
    __shared__ float tile[32][33];
    int kb = blockIdx.x * 32, nb = blockIdx.y * 32;
    int tx = threadIdx.x, ty = threadIdx.y;          // (32, 8)
#pragma unroll
    for (int i = 0; i < 32; i += 8)
        tile[ty + i][tx] = W[(size_t)(kb + ty + i) * N + nb + tx];
    __syncthreads();
#pragma unroll
    for (int i = 0; i < 32; i += 8)
        Wt[(size_t)(nb + ty + i) * K + kb + tx] = f2bf(tile[tx][ty + i] * scale);
}

// ---------------- LayerNorm + cast: xn = bf16(LN(x)*gamma), xb = bf16(x) ----------------
__global__ __launch_bounds__(256) void ln_cast(const float* __restrict__ x, const float* __restrict__ gamma,
                                               u16* __restrict__ xn, u16* __restrict__ xb) {
    const int row = blockIdx.x;          // 4096 rows of 1024
    const int t = threadIdx.x;           // 256 threads, 4 floats each
    const float4 v = ((const float4*)(x + (size_t)row * 1024))[t];
    float s  = v.x + v.y + v.z + v.w;
    float s2 = v.x * v.x + v.y * v.y + v.z * v.z + v.w * v.w;
#pragma unroll
    for (int off = 32; off; off >>= 1) { s += __shfl_down(s, off); s2 += __shfl_down(s2, off); }
    __shared__ float red[2][4];
    const int w = t >> 6, lane = t & 63;
    if (lane == 0) { red[0][w] = s; red[1][w] = s2; }
    __syncthreads();
    s  = red[0][0] + red[0][1] + red[0][2] + red[0][3];
    s2 = red[1][0] + red[1][1] + red[1][2] + red[1][3];
    const float mu  = s * (1.0f / 1024.0f);
    const float var = s2 * (1.0f / 1024.0f) - mu * mu;
    const float rs  = rsqrtf(var + 1e-5f);
    const float4 g = ((const float4*)gamma)[t];
    u16x4 on, ob;
    on.x = f2bf((v.x - mu) * rs * g.x); on.y = f2bf((v.y - mu) * rs * g.y);
    on.z = f2bf((v.z - mu) * rs * g.z); on.w = f2bf((v.w - mu) * rs * g.w);
    ob.x = f2bf(v.x); ob.y = f2bf(v.y); ob.z = f2bf(v.z); ob.w = f2bf(v.w);
    ((u16x4*)(xn + (size_t)row * 1024))[t] = on;
    ((u16x4*)(xb + (size_t)row * 1024))[t] = ob;
}

// ---------------- GEMM: C[M,N] = A[M,K] @ Bt[N,K]^T (bf16 in, f32 acc) ----------------
template<int BM, int BN, int EPI>
__global__ __launch_bounds__(256) void gemm_bt(const u16* __restrict__ A, const u16* __restrict__ Bt,
                                               u16* __restrict__ Cb, float* __restrict__ Cf,
                                               u16* __restrict__ Cv, int M, int N, int K) {
    constexpr int WM = BM / 2, WN = BN / 2, FM = WM / 16, FN = WN / 16;
    constexpr int CHA = BM * 4, CH = (BM + BN) * 4, ITERS = CH / 256;  // 16B chunks, BK=32
    __shared__ __align__(16) u16 lds[2][(BM + BN) * 32];
    const int tid = threadIdx.x;
    const int m0 = blockIdx.x * BM, n0 = blockIdx.y * BN;
    const int w = tid >> 6, lane = tid & 63, cl = lane & 15, kg = lane >> 4;
    const int wr = w >> 1, wc = w & 1;

    auto stage = [&](int buf, int k0) {
#pragma unroll
        for (int it = 0; it < ITERS; ++it) {
            int c = it * 256 + tid;
            const u16* g;
            if (c < CHA) { int r = c >> 2, cc = c & 3; g = A  + (size_t)(m0 + r) * K + k0 + cc * 8; }
            else { int c2 = c - CHA; int r = c2 >> 2, cc = c2 & 3; g = Bt + (size_t)(n0 + r) * K + k0 + cc * 8; }
            __builtin_amdgcn_global_load_lds(
                (const __attribute__((address_space(1))) unsigned int*)g,
                (__attribute__((address_space(3))) unsigned int*)&lds[buf][c * 8], 16, 0, 0);
        }
    };

    const f32x4 zero = {0.f, 0.f, 0.f, 0.f};
    f32x4 acc[FM][FN];
#pragma unroll
    for (int m = 0; m < FM; m++)
#pragma unroll
        for (int n = 0; n < FN; n++) acc[m][n] = zero;

    const int KT = K / 32;
    stage(0, 0);
    for (int t = 0; t < KT; ++t) {
        __syncthreads();
        if (t + 1 < KT) stage((t + 1) & 1, (t + 1) * 32);
        const u16* As = &lds[t & 1][0];
        const u16* Bs = &lds[t & 1][BM * 32];
        bf16x8 af[FM], bfr[FN];
#pragma unroll
        for (int m = 0; m < FM; m++) af[m]  = ldbf8(As + (wr * WM + m * 16 + cl) * 32 + kg * 8);
#pragma unroll
        for (int n = 0; n < FN; n++) bfr[n] = ldbf8(Bs + (wc * WN + n * 16 + cl) * 32 + kg * 8);
#pragma unroll
        for (int m = 0; m < FM; m++)
#pragma unroll
            for (int n = 0; n < FN; n++) acc[m][n] = mfma16(af[m], bfr[n], acc[m][n]);
    }

#pragma unroll
    for (int m = 0; m < FM; m++)
#pragma unroll
        for (int n = 0; n < FN; n++)
#pragma unroll
            for (int r = 0; r < 4; r++) {
                const int row = m0 + wr * WM + m * 16 + kg * 4 + r;
                const int col = n0 + wc * WN + n * 16 + cl;
                const float v = acc[m][n][r];
                if constexpr (EPI == 0) Cb[(size_t)row * N + col] = f2bf(v);
                else if constexpr (EPI == 1) Cf[(size_t)row * N + col] = v;
                else {
                    if (col < 64) Cb[(size_t)row * 64 + col] = f2bf(v);
                    else { int bb = row >> 11, s = row & 2047;
                           Cv[((size_t)bb * 64 + (col - 64)) * 2048 + s] = f2bf(v); }
                }
            }
}

// ---------------- kmax: kmax2[b] = max_row ||k_row||^2 (atomicMax on positive-float bits) --------
__global__ __launch_bounds__(256) void kmax_kernel(const u16* __restrict__ kb, unsigned* __restrict__ kmax2) {
    const int b = blockIdx.x >> 5, blk = blockIdx.x & 31;    // 64 rows per block
    const int tid = threadIdx.x;
    const int r = blk * 64 + (tid >> 2), c4 = tid & 3;       // 4 threads/row, 16 elems each
    const u16* kp = kb + ((size_t)b * 2048 + r) * 64 + c4 * 16;
    float s2 = 0.f;
#pragma unroll
    for (int i = 0; i < 2; i++) {
        u16x8 v = ((const u16x8*)kp)[i];
#pragma unroll
        for (int j = 0; j < 8; j++) {
            const float f = __uint_as_float(((unsigned)v[j]) << 16);
            s2 = fmaf(f, f, s2);
        }
    }
    s2 += __shfl_xor(s2, 1); s2 += __shfl_xor(s2, 2);        // row sum
    float mx = s2;
#pragma unroll
    for (int off = 4; off < 64; off <<= 1) mx = fmaxf(mx, __shfl_xor(mx, off));
    __shared__ float red[4];
    if ((tid & 63) == 0) red[tid >> 6] = mx;
    __syncthreads();
    if (tid == 0) {
        mx = fmaxf(fmaxf(red[0], red[1]), fmaxf(red[2], red[3]));
        atomicMax(&kmax2[b], __float_as_uint(mx));           // valid for non-negative floats
    }
}

// ---------------- causal flash attention, MQA, Dh=64, LDS-staged K/V, fixed-bound softmax --------
// Block = (b,h, q-tiles 4g..4g+3); wave w owns q-tile 4g+w. Per kv-tile: K staged via
// global_load_lds (src-XOR-swizzled), V^T reg-staged into 80B-padded rows. 1 barrier/tile.
// m_i = ||q_i||*kmax >= max_j s_ij (Cauchy-Schwarz): no online max/rescale; merge-free.
__global__ __launch_bounds__(256) void attn_fwd(const u16* __restrict__ q, const u16* __restrict__ k,
                                                const u16* __restrict__ vt, const unsigned* __restrict__ kmax2,
                                                u16* __restrict__ o) {
    constexpr int S = 2048;
    const int bid = blockIdx.x;                  // (15-g)*32 + bh : big-g first
    const int bh = bid & 31, g = 15 - (bid >> 5);
    const int h = bh & 15, b = bh >> 4;
    const int tid = threadIdx.x, w = tid >> 6, lane = tid & 63;
    const int l31 = lane & 31;
    const bool hi = (lane & 32) != 0;
    const int hi1 = hi ? 1 : 0, hi8 = hi ? 8 : 0;
    const int tw = 4 * g + w, tmax = 4 * g + 3;  // wave's q-tile index / block's last kv tile
    const int q0 = tw * 32;
    const size_t bS = (size_t)b * S;

    // LDS: kls[2][32*64] (4KB each, XOR-swizzled cols) + vls[2][64*40] (80B rows).
    // Epilogue obuf[4][32*72] aliases the whole region (after barrier).
    __shared__ __align__(16) u16 smem[9216];
    u16* kls0 = smem;            u16* kls1 = smem + 2048;
    u16* vls0 = smem + 4096;     u16* vls1 = smem + 4096 + 2560;

    auto stageK = [&](int jt, u16* kdst) {
        const int r = tid >> 3, c = tid & 7;     // 32 rows x 8 chunks of 16B
        const u16* gp = k + (bS + jt * 32 + r) * 64 + ((c ^ (r & 7)) * 8);  // src pre-swizzled
        __builtin_amdgcn_global_load_lds(
            (const __attribute__((address_space(1))) unsigned int*)gp,
            (__attribute__((address_space(3))) unsigned int*)(kdst + tid * 8), 16, 0, 0);
    };
    auto loadV = [&](int jt) -> u16x8 {          // V^T tile [64 d][32 kv], 16B per thread
        const int rv = tid >> 2, c4 = tid & 3;
        return *(const u16x8*)(vt + ((size_t)b * 64 + rv) * S + jt * 32 + c4 * 8);
    };
    auto writeV = [&](u16* vdst, u16x8 v) {
        const int rv = tid >> 2, c4 = tid & 3;
        *(u16x8*)(vdst + rv * 40 + c4 * 8) = v;  // 80B row stride -> conflict-free reads
    };

    bf16x8 qf[4];                                // Q B-frags: col=q=l31, k=hi*8+j (+16*sub)
    {
        const u16* qp = q + (bS + q0 + l31) * 1024 + h * 64 + hi8;
#pragma unroll
        for (int sub = 0; sub < 4; sub++) qf[sub] = ldbf8(qp + sub * 16);
    }
    // per-row softmax bound: m = ||q_row|| * kmax_b (q already has SCALE*log2e folded)
    float qn2 = 0.f;
#pragma unroll
    for (int sub = 0; sub < 4; sub++) {
        const u16x8 uv = __builtin_bit_cast(u16x8, qf[sub]);
#pragma unroll
        for (int j = 0; j < 8; j++) {
            const float v = __uint_as_float(((unsigned)uv[j]) << 16);
            qn2 = fmaf(v, v, qn2);
        }
    }
    qn2 = combine_sum(qn2);
    const float mB = sqrtf(qn2) * sqrtf(__uint_as_float(kmax2[b]));

    f32x16 accO0, accO1;                         // O^T d-tiles: col=q=l31, row(r,hi)=d
#pragma unroll
    for (int r = 0; r < 16; r++) { accO0[r] = 0.f; accO1[r] = 0.f; }
    float l_run = 0.f;

    auto body = [&](int jt, const u16* kcur, const u16* vcur) {
        bf16x8 kf[4];
#pragma unroll
        for (int sub = 0; sub < 4; sub++)
            kf[sub] = ldbf8(kcur + l31 * 64 + (((sub * 2 + hi1) ^ (l31 & 7)) * 8));
        f32x16 s;
#pragma unroll
        for (int r = 0; r < 16; r++) s[r] = 0.f;
#pragma unroll
        for (int sub = 0; sub < 4; sub++) s = mfma32x(kf[sub], qf[sub], s);
        bf16x8 vf00 = ldbf8(vcur + l31 * 40 + hi8);
        bf16x8 vf01 = ldbf8(vcur + l31 * 40 + 16 + hi8);
        bf16x8 vf10 = ldbf8(vcur + (32 + l31) * 40 + hi8);
        bf16x8 vf11 = ldbf8(vcur + (32 + l31) * 40 + 16 + hi8);
        if (jt == tw) {                          // diagonal tile: causal mask
#pragma unroll
            for (int r = 0; r < 16; r++) {
                const int kvl = (r & 3) + 8 * (r >> 2) + (hi ? 4 : 0);
                if (kvl > l31) s[r] = -1e30f;
            }
        }
        float p0 = 0.f, p1 = 0.f;
#pragma unroll
        for (int r = 0; r < 16; r += 2) {
            const float ea = exp2a(s[r] - mB);
            const float eb = exp2a(s[r + 1] - mB);
            s[r] = ea; s[r + 1] = eb;
            p0 += ea; p1 += eb;
        }
        l_run += p0 + p1;
        unsigned w0 = cvtpk(s[0], s[1]),  w1 = cvtpk(s[2], s[3]);
        unsigned w2 = cvtpk(s[4], s[5]),  w3 = cvtpk(s[6], s[7]);
        u32x2 r02 = permswap2(w0, w2), r13 = permswap2(w1, w3);
        bf16x8 pf0 = pack4(r02[0], r13[0], r02[1], r13[1]);
        unsigned y0 = cvtpk(s[8], s[9]),   y1 = cvtpk(s[10], s[11]);
        unsigned y2 = cvtpk(s[12], s[13]), y3 = cvtpk(s[14], s[15]);
        u32x2 t02 = permswap2(y0, y2), t13 = permswap2(y1, y3);
        bf16x8 pf1 = pack4(t02[0], t13[0], t02[1], t13[1]);
        accO0 = mfma32x(vf00, pf0, accO0);
        accO0 = mfma32x(vf01, pf1, accO0);
        accO1 = mfma32x(vf10, pf0, accO1);
        accO1 = mfma32x(vf11, pf1, accO1);
    };

    // ---- pipelined kv loop: 1 barrier/tile, stage(jt+1) issued right after barrier ----
    stageK(0, kls0);
    u16x8 vA = loadV(0), vB;
    for (int jt = 0; jt <= tmax; jt += 2) {      // tmax odd -> even tile count
        // even tile -> buf0
        asm volatile("s_waitcnt vmcnt(0)" ::: "memory");     // K in kls0, V in vA
        writeV(vls0, vA);
        asm volatile("s_waitcnt lgkmcnt(0)" ::: "memory");
        __builtin_amdgcn_s_barrier();                        // publish buf0; prev reads of buf1 done
        if (jt + 1 <= tmax) { stageK(jt + 1, kls1); vB = loadV(jt + 1); }
        if (jt <= tw) body(jt, kls0, vls0);
        // odd tile -> buf1
        asm volatile("s_waitcnt vmcnt(0)" ::: "memory");
        writeV(vls1, vB);
        asm volatile("s_waitcnt lgkmcnt(0)" ::: "memory");
        __builtin_amdgcn_s_barrier();
        if (jt + 2 <= tmax) { stageK(jt + 2, kls0); vA = loadV(jt + 2); }
        if (jt + 1 <= tw) body(jt + 1, kls1, vls1);
    }

    // ---- epilogue: O^T -> obuf (aliases stage bufs; barrier first) -> coalesced global ----
    __builtin_amdgcn_s_barrier();
    const float rl = 1.0f / combine_sum(l_run);
    u16* lb = smem + w * 2304;                   // [32 q][72 u16] per wave
#pragma unroll
    for (int i = 0; i < 8; i++) {
        const int d = ((2 * i) & 3) + 8 * ((2 * i) >> 2) + (hi ? 4 : 0);
        *(unsigned*)&lb[l31 * 72 + d]      = cvtpk(accO0[2 * i] * rl, accO0[2 * i + 1] * rl);
        *(unsigned*)&lb[l31 * 72 + 32 + d] = cvtpk(accO1[2 * i] * rl, accO1[2 * i + 1] * rl);
    }
    asm volatile("s_waitcnt lgkmcnt(0)" ::: "memory");
#pragma unroll
    for (int i = 0; i < 4; i++) {
        const int qq = i * 8 + (lane >> 3), dd = (lane & 7) * 8;
        *(u16x8*)(o + (bS + q0 + qq) * 1024 + h * 64 + dd) = *(const u16x8*)&lb[qq * 72 + dd];
    }
}

// ---------------- launcher ----------------
extern "C" void kernel_launch(void* const* d_in, const int* in_sizes, int n_in,
                              void* d_out, int out_size, void* d_ws, size_t ws_size,
                              hipStream_t stream) {
    const float* x     = (const float*)d_in[0];
    const float* gamma = (const float*)d_in[1];
    const float* Wq    = (const float*)d_in[2];
    const float* Wkv   = (const float*)d_in[3];
    const float* Wo    = (const float*)d_in[4];
    float* out = (float*)d_out;
    char* ws = (char*)d_ws;

    u16* Wq_t  = (u16*)(ws + 0);             // 2 MB
    u16* Wo_t  = (u16*)(ws + (2u << 20));    // 2 MB
    u16* Wkv_t = (u16*)(ws + (4u << 20));    // 256 KB
    u16* xn    = (u16*)(ws + 4456448u);      // 8 MB
    u16* xb    = (u16*)(ws + 12845056u);     // 8 MB (free after kv-gemm; reused for kmax2)
    u16* qb    = (u16*)(ws + 21233664u);     // 8 MB
    u16* kb    = (u16*)(ws + 29622272u);     // 512 KB
    u16* vtb   = (u16*)(ws + 30146560u);     // 512 KB
    u16* attb  = (u16*)(ws + 30670848u);     // 8 MB
    unsigned* kmax2 = (unsigned*)xb;         // 8 B, written after xb's last use

    const dim3 tb(32, 8);
    const float qscale = 0.125f * 1.44269504f;   // SCALE * log2(e) folded into Wq
    transpose_cast<<<dim3(32, 32), tb, 0, stream>>>(Wq,  Wq_t,  1024, 1024, qscale);
    transpose_cast<<<dim3(32, 4),  tb, 0, stream>>>(Wkv, Wkv_t, 1024, 128, 1.0f);
    transpose_cast<<<dim3(32, 32), tb, 0, stream>>>(Wo,  Wo_t,  1024, 1024, 1.0f);

    ln_cast<<<4096, 256, 0, stream>>>(x, gamma, xn, xb);

    gemm_bt<128, 128, 0><<<dim3(32, 8), 256, 0, stream>>>(xn, Wq_t, qb, nullptr, nullptr, 4096, 1024, 1024);
    gemm_bt<64, 64, 2><<<dim3(64, 2), 256, 0, stream>>>(xb, Wkv_t, kb, nullptr, vtb, 4096, 128, 1024);
    hipMemsetAsync(kmax2, 0, 8, stream);
    kmax_kernel<<<64, 256, 0, stream>>>(kb, kmax2);
    attn_fwd<<<512, 256, 0, stream>>>(qb, kb, vtb, kmax2, attb);
    gemm_bt<128, 128, 1><<<dim3(32, 8), 256, 0, stream>>>(attb, Wo_t, nullptr, out, nullptr, 4096, 1024, 1024);
}

// Round 7
// 105.284 us; speedup vs baseline: 1.4411x; 1.1264x over previous
//
#include <hip/hip_runtime.h>

typedef unsigned short u16;
typedef __attribute__((ext_vector_type(8))) u16    u16x8;
typedef __attribute__((ext_vector_type(4))) u16    u16x4;
typedef __attribute__((ext_vector_type(2))) unsigned u32x2;
typedef __attribute__((ext_vector_type(8))) __bf16 bf16x8;
typedef __attribute__((ext_vector_type(4))) float  f32x4;
typedef __attribute__((ext_vector_type(16))) float f32x16;

__device__ __forceinline__ u16 f2bf(float f) {
    unsigned u = __float_as_uint(f);
    u += 0x7fffu + ((u >> 16) & 1u);   // RNE
    return (u16)(u >> 16);
}
__device__ __forceinline__ bf16x8 ldbf8(const u16* p) {
    return __builtin_bit_cast(bf16x8, *(const u16x8*)p);
}
__device__ __forceinline__ f32x4 mfma16(bf16x8 a, bf16x8 b, f32x4 c) {
    return __builtin_amdgcn_mfma_f32_16x16x32_bf16(a, b, c, 0, 0, 0);
}
__device__ __forceinline__ f32x16 mfma32x(bf16x8 a, bf16x8 b, f32x16 c) {
    return __builtin_amdgcn_mfma_f32_32x32x16_bf16(a, b, c, 0, 0, 0);
}
__device__ __forceinline__ float exp2a(float x) {
    float r; asm("v_exp_f32 %0, %1" : "=v"(r) : "v"(x)); return r;
}
__device__ __forceinline__ unsigned cvtpk(float lo, float hiv) {
    unsigned r; asm("v_cvt_pk_bf16_f32 %0, %1, %2" : "=v"(r) : "v"(lo), "v"(hiv)); return r;
}
__device__ __forceinline__ u32x2 permswap2(unsigned a, unsigned b) {
    return __builtin_amdgcn_permlane32_swap(a, b, false, false);
}
__device__ __forceinline__ float combine_sum(float x) {   // x + partner-half x (orientation-robust)
    u32x2 pr = permswap2(__float_as_uint(x), __float_as_uint(x));
    return __uint_as_float(pr[0]) + __uint_as_float(pr[1]);
}
__device__ __forceinline__ bf16x8 pack4(unsigned a, unsigned b, unsigned c, unsigned d) {
    union { unsigned u[4]; bf16x8 v; } t; t.u[0] = a; t.u[1] = b; t.u[2] = c; t.u[3] = d; return t.v;
}

// ---------------- weight transpose + cast:  Wt[n][k] = bf16(W[k][n] * scale) ----------------
__global__ void transpose_cast(const float* __restrict__ W, u16* __restrict__ Wt, int K, int N, float scale) {
    __shared__ float tile[32][33];
    int kb = blockIdx.x * 32, nb = blockIdx.y * 32;
    int tx = threadIdx.x, ty = threadIdx.y;          // (32, 8)
#pragma unroll
    for (int i = 0; i < 32; i += 8)
        tile[ty + i][tx] = W[(size_t)(kb + ty + i) * N + nb + tx];
    __syncthreads();
#pragma unroll
    for (int i = 0; i < 32; i += 8)
        Wt[(size_t)(nb + ty + i) * K + kb + tx] = f2bf(tile[tx][ty + i] * scale);
}

// ---------------- LayerNorm + cast: xn = bf16(LN(x)*gamma), xb = bf16(x) ----------------
__global__ __launch_bounds__(256) void ln_cast(const float* __restrict__ x, const float* __restrict__ gamma,
                                               u16* __restrict__ xn, u16* __restrict__ xb) {
    const int row = blockIdx.x;          // 4096 rows of 1024
    const int t = threadIdx.x;           // 256 threads, 4 floats each
    const float4 v = ((const float4*)(x + (size_t)row * 1024))[t];
    float s  = v.x + v.y + v.z + v.w;
    float s2 = v.x * v.x + v.y * v.y + v.z * v.z + v.w * v.w;
#pragma unroll
    for (int off = 32; off; off >>= 1) { s += __shfl_down(s, off); s2 += __shfl_down(s2, off); }
    __shared__ float red[2][4];
    const int w = t >> 6, lane = t & 63;
    if (lane == 0) { red[0][w] = s; red[1][w] = s2; }
    __syncthreads();
    s  = red[0][0] + red[0][1] + red[0][2] + red[0][3];
    s2 = red[1][0] + red[1][1] + red[1][2] + red[1][3];
    const float mu  = s * (1.0f / 1024.0f);
    const float var = s2 * (1.0f / 1024.0f) - mu * mu;
    const float rs  = rsqrtf(var + 1e-5f);
    const float4 g = ((const float4*)gamma)[t];
    u16x4 on, ob;
    on.x = f2bf((v.x - mu) * rs * g.x); on.y = f2bf((v.y - mu) * rs * g.y);
    on.z = f2bf((v.z - mu) * rs * g.z); on.w = f2bf((v.w - mu) * rs * g.w);
    ob.x = f2bf(v.x); ob.y = f2bf(v.y); ob.z = f2bf(v.z); ob.w = f2bf(v.w);
    ((u16x4*)(xn + (size_t)row * 1024))[t] = on;
    ((u16x4*)(xb + (size_t)row * 1024))[t] = ob;
}

// ---------------- GEMM: C[M,N] = A[M,K] @ Bt[N,K]^T (bf16 in, f32 acc) ----------------
template<int BM, int BN, int EPI>
__global__ __launch_bounds__(256) void gemm_bt(const u16* __restrict__ A, const u16* __restrict__ Bt,
                                               u16* __restrict__ Cb, float* __restrict__ Cf,
                                               u16* __restrict__ Cv, int M, int N, int K) {
    constexpr int WM = BM / 2, WN = BN / 2, FM = WM / 16, FN = WN / 16;
    constexpr int CHA = BM * 4, CH = (BM + BN) * 4, ITERS = CH / 256;  // 16B chunks, BK=32
    __shared__ __align__(16) u16 lds[2][(BM + BN) * 32];
    const int tid = threadIdx.x;
    const int m0 = blockIdx.x * BM, n0 = blockIdx.y * BN;
    const int w = tid >> 6, lane = tid & 63, cl = lane & 15, kg = lane >> 4;
    const int wr = w >> 1, wc = w & 1;

    auto stage = [&](int buf, int k0) {
#pragma unroll
        for (int it = 0; it < ITERS; ++it) {
            int c = it * 256 + tid;
            const u16* g;
            if (c < CHA) { int r = c >> 2, cc = c & 3; g = A  + (size_t)(m0 + r) * K + k0 + cc * 8; }
            else { int c2 = c - CHA; int r = c2 >> 2, cc = c2 & 3; g = Bt + (size_t)(n0 + r) * K + k0 + cc * 8; }
            __builtin_amdgcn_global_load_lds(
                (const __attribute__((address_space(1))) unsigned int*)g,
                (__attribute__((address_space(3))) unsigned int*)&lds[buf][c * 8], 16, 0, 0);
        }
    };

    const f32x4 zero = {0.f, 0.f, 0.f, 0.f};
    f32x4 acc[FM][FN];
#pragma unroll
    for (int m = 0; m < FM; m++)
#pragma unroll
        for (int n = 0; n < FN; n++) acc[m][n] = zero;

    const int KT = K / 32;
    stage(0, 0);
    for (int t = 0; t < KT; ++t) {
        __syncthreads();
        if (t + 1 < KT) stage((t + 1) & 1, (t + 1) * 32);
        const u16* As = &lds[t & 1][0];
        const u16* Bs = &lds[t & 1][BM * 32];
        bf16x8 af[FM], bfr[FN];
#pragma unroll
        for (int m = 0; m < FM; m++) af[m]  = ldbf8(As + (wr * WM + m * 16 + cl) * 32 + kg * 8);
#pragma unroll
        for (int n = 0; n < FN; n++) bfr[n] = ldbf8(Bs + (wc * WN + n * 16 + cl) * 32 + kg * 8);
#pragma unroll
        for (int m = 0; m < FM; m++)
#pragma unroll
            for (int n = 0; n < FN; n++) acc[m][n] = mfma16(af[m], bfr[n], acc[m][n]);
    }

#pragma unroll
    for (int m = 0; m < FM; m++)
#pragma unroll
        for (int n = 0; n < FN; n++)
#pragma unroll
            for (int r = 0; r < 4; r++) {
                const int row = m0 + wr * WM + m * 16 + kg * 4 + r;
                const int col = n0 + wc * WN + n * 16 + cl;
                const float v = acc[m][n][r];
                if constexpr (EPI == 0) Cb[(size_t)row * N + col] = f2bf(v);
                else if constexpr (EPI == 1) Cf[(size_t)row * N + col] = v;
                else {
                    if (col < 64) Cb[(size_t)row * 64 + col] = f2bf(v);
                    else { int bb = row >> 11, s = row & 2047;
                           Cv[((size_t)bb * 64 + (col - 64)) * 2048 + s] = f2bf(v); }
                }
            }
}

// ---------------- kmax: kmax2[b] = max_row ||k_row||^2 (atomicMax on positive-float bits) --------
__global__ __launch_bounds__(256) void kmax_kernel(const u16* __restrict__ kb, unsigned* __restrict__ kmax2) {
    const int b = blockIdx.x >> 5, blk = blockIdx.x & 31;    // 64 rows per block
    const int tid = threadIdx.x;
    const int r = blk * 64 + (tid >> 2), c4 = tid & 3;       // 4 threads/row, 16 elems each
    const u16* kp = kb + ((size_t)b * 2048 + r) * 64 + c4 * 16;
    float s2 = 0.f;
#pragma unroll
    for (int i = 0; i < 2; i++) {
        u16x8 v = ((const u16x8*)kp)[i];
#pragma unroll
        for (int j = 0; j < 8; j++) {
            const float f = __uint_as_float(((unsigned)v[j]) << 16);
            s2 = fmaf(f, f, s2);
        }
    }
    s2 += __shfl_xor(s2, 1); s2 += __shfl_xor(s2, 2);        // row sum
    float mx = s2;
#pragma unroll
    for (int off = 4; off < 64; off <<= 1) mx = fmaxf(mx, __shfl_xor(mx, off));
    __shared__ float red[4];
    if ((tid & 63) == 0) red[tid >> 6] = mx;
    __syncthreads();
    if (tid == 0) {
        mx = fmaxf(fmaxf(red[0], red[1]), fmaxf(red[2], red[3]));
        atomicMax(&kmax2[b], __float_as_uint(mx));           // valid for non-negative floats
    }
}

// ---------------- causal flash attention, MQA, Dh=64, balanced pairs + kv-parity split ----------
// Block = (b,h,p): 4 waves = (pair pw) x (kv-parity par). Wave handles q-tiles t1=2p+pw and
// t2=63-t1 over kv tiles jt≡par(2), jt≤t. One shared kv sweep stages 2 tiles/iter into LDS.
// Fixed-bound softmax (m_i = ||q_i||*kmax): parity merge = plain add in LDS.
__global__ __launch_bounds__(256, 2) void attn_fwd(const u16* __restrict__ q, const u16* __restrict__ k,
                                                   const u16* __restrict__ vt, const unsigned* __restrict__ kmax2,
                                                   u16* __restrict__ o) {
    constexpr int S = 2048;
    const int bid = blockIdx.x;
    const int p = (bid < 256) ? (bid >> 5) : (15 - ((bid - 256) >> 5));  // pair long+short sweeps per CU
    const int bh = bid & 31;
    const int h = bh & 15, b = bh >> 4;
    const int tid = threadIdx.x, w = tid >> 6, lane = tid & 63;
    const int pw = w & 1, par = w >> 1;
    const int l31 = lane & 31;
    const bool hi = (lane & 32) != 0;
    const int hi1 = hi ? 1 : 0, hi8 = hi ? 8 : 0;
    const int t1 = 2 * p + pw, t2 = 63 - t1;
    const int iters = 32 - p;                    // kv tiles 0..63-2p, two per iteration
    const size_t bS = (size_t)b * S;

    // smem 36864B: stage region (kls 4x4KB + vls 4x5KB = 36KB) ∪ merge (4x64x36 f32) ∪ epi (18KB)
    __shared__ __align__(16) u16 smem[18432];

    auto stageK = [&](int jt, int buf, int tl) {             // one 32x64 K tile, swizzled source
        const int r = tid >> 3, c = tid & 7;
        const u16* gp = k + (bS + jt * 32 + r) * 64 + ((c ^ (r & 7)) * 8);
        __builtin_amdgcn_global_load_lds(
            (const __attribute__((address_space(1))) unsigned int*)gp,
            (__attribute__((address_space(3))) unsigned int*)(smem + (buf * 2 + tl) * 2048 + tid * 8), 16, 0, 0);
    };
    auto loadV = [&](int jt) -> u16x8 {                      // V^T tile [64 d][32 kv]
        const int rv = tid >> 2, c4 = tid & 3;
        return *(const u16x8*)(vt + ((size_t)b * 64 + rv) * S + jt * 32 + c4 * 8);
    };
    auto writeV = [&](int buf, int tl, u16x8 v) {
        const int rv = tid >> 2, c4 = tid & 3;
        *(u16x8*)(smem + 8192 + (buf * 2 + tl) * 2560 + rv * 40 + c4 * 8) = v;
    };

    const float kmaxb = sqrtf(__uint_as_float(kmax2[b]));
    bf16x8 qf1[4], qf2[4];
    float mB1, mB2;
    auto qload = [&](int t, bf16x8 (&qf)[4]) -> float {
        const u16* qp = q + (bS + t * 32 + l31) * 1024 + h * 64 + hi8;
        float qn2 = 0.f;
#pragma unroll
        for (int sub = 0; sub < 4; sub++) {
            qf[sub] = ldbf8(qp + sub * 16);
            const u16x8 uv = __builtin_bit_cast(u16x8, qf[sub]);
#pragma unroll
            for (int j = 0; j < 8; j++) {
                const float v = __uint_as_float(((unsigned)uv[j]) << 16);
                qn2 = fmaf(v, v, qn2);
            }
        }
        return sqrtf(combine_sum(qn2)) * kmaxb;
    };
    mB1 = qload(t1, qf1);
    mB2 = qload(t2, qf2);

    f32x16 a1lo, a1hi, a2lo, a2hi;               // O^T accumulators for q1, q2
#pragma unroll
    for (int r = 0; r < 16; r++) { a1lo[r] = 0.f; a1hi[r] = 0.f; a2lo[r] = 0.f; a2hi[r] = 0.f; }
    float l1 = 0.f, l2 = 0.f;

    auto process = [&](const bf16x8 (&qf)[4], const bf16x8 (&kf)[4],
                       const bf16x8& vf00, const bf16x8& vf01, const bf16x8& vf10, const bf16x8& vf11,
                       f32x16& a0, f32x16& a1, float& lr, float mB, bool diag) {
        f32x16 s;
#pragma unroll
        for (int r = 0; r < 16; r++) s[r] = 0.f;
#pragma unroll
        for (int sub = 0; sub < 4; sub++) s = mfma32x(kf[sub], qf[sub], s);
        if (diag) {
#pragma unroll
            for (int r = 0; r < 16; r++) {
                const int kvl = (r & 3) + 8 * (r >> 2) + (hi ? 4 : 0);
                if (kvl > l31) s[r] = -1e30f;
            }
        }
        float p0 = 0.f, p1 = 0.f;
#pragma unroll
        for (int r = 0; r < 16; r += 2) {
            const float ea = exp2a(s[r] - mB);
            const float eb = exp2a(s[r + 1] - mB);
            s[r] = ea; s[r + 1] = eb;
            p0 += ea; p1 += eb;
        }
        lr += p0 + p1;
        unsigned w0 = cvtpk(s[0], s[1]),  w1 = cvtpk(s[2], s[3]);
        unsigned w2 = cvtpk(s[4], s[5]),  w3 = cvtpk(s[6], s[7]);
        u32x2 r02 = permswap2(w0, w2), r13 = permswap2(w1, w3);
        bf16x8 pf0 = pack4(r02[0], r13[0], r02[1], r13[1]);
        unsigned y0 = cvtpk(s[8], s[9]),   y1 = cvtpk(s[10], s[11]);
        unsigned y2 = cvtpk(s[12], s[13]), y3 = cvtpk(s[14], s[15]);
        u32x2 t02 = permswap2(y0, y2), t13 = permswap2(y1, y3);
        bf16x8 pf1 = pack4(t02[0], t13[0], t02[1], t13[1]);
        a0 = mfma32x(vf00, pf0, a0);
        a0 = mfma32x(vf01, pf1, a0);
        a1 = mfma32x(vf10, pf0, a1);
        a1 = mfma32x(vf11, pf1, a1);
    };

    // ---- shared kv sweep: 2 tiles/iter, double-buffered; 1 __syncthreads per iter ----
    stageK(0, 0, 0); stageK(1, 0, 1);
    u16x8 v0 = loadV(0), v1 = loadV(1);
    for (int i = 0; i < iters; i++) {
        const int buf = i & 1;
        writeV(buf, 0, v0); writeV(buf, 1, v1);
        __syncthreads();                         // drains vmcnt (K pair i) + lgkm (V writes), then barrier
        if (i + 1 < iters) {
            stageK(2 * i + 2, buf ^ 1, 0); stageK(2 * i + 3, buf ^ 1, 1);
            v0 = loadV(2 * i + 2); v1 = loadV(2 * i + 3);
        }
        const int jt = 2 * i + par;
        if (jt <= t2) {
            const u16* kcur = smem + (buf * 2 + par) * 2048;
            const u16* vcur = smem + 8192 + (buf * 2 + par) * 2560;
            bf16x8 kf[4];
#pragma unroll
            for (int sub = 0; sub < 4; sub++)
                kf[sub] = ldbf8(kcur + l31 * 64 + (((sub * 2 + hi1) ^ (l31 & 7)) * 8));
            const bf16x8 vf00 = ldbf8(vcur + l31 * 40 + hi8);
            const bf16x8 vf01 = ldbf8(vcur + l31 * 40 + 16 + hi8);
            const bf16x8 vf10 = ldbf8(vcur + (32 + l31) * 40 + hi8);
            const bf16x8 vf11 = ldbf8(vcur + (32 + l31) * 40 + 16 + hi8);
            if (jt <= t1) process(qf1, kf, vf00, vf01, vf10, vf11, a1lo, a1hi, l1, mB1, jt == t1);
            process(qf2, kf, vf00, vf01, vf10, vf11, a2lo, a2hi, l2, mB2, jt == t2);
        }
    }
    float l1t = combine_sum(l1), l2t = combine_sum(l2);

    // ---- parity merge (plain add; fixed bound -> no rescale). Slot[pw][0]=q1 from par1, [1]=q2 from par0.
    float* fm = (float*)smem;
    __syncthreads();                             // all stage-buffer reads done; safe to alias
    {
        float* dst = fm + (((pw * 2) + (par ? 0 : 1)) * 64 + lane) * 36;
        if (par) { *(f32x16*)dst = a1lo; *(f32x16*)(dst + 16) = a1hi; dst[32] = l1t; }
        else     { *(f32x16*)dst = a2lo; *(f32x16*)(dst + 16) = a2hi; dst[32] = l2t; }
    }
    __syncthreads();
    {
        const float* src = fm + (((pw * 2) + (par ? 1 : 0)) * 64 + lane) * 36;
        const f32x16 s0 = *(const f32x16*)src;
        const f32x16 s1 = *(const f32x16*)(src + 16);
        if (par) {
#pragma unroll
            for (int r = 0; r < 16; r++) { a2lo[r] += s0[r]; a2hi[r] += s1[r]; }
            l2t += src[32];
        } else {
#pragma unroll
            for (int r = 0; r < 16; r++) { a1lo[r] += s0[r]; a1hi[r] += s1[r]; }
            l1t += src[32];
        }
    }
    __syncthreads();                             // merge reads done; safe to alias for epilogue

    // ---- epilogue: wave par=0 owns q1, par=1 owns q2. O^T -> LDS [32q][72] -> coalesced ----
    auto epi = [&](const f32x16& a0, const f32x16& a1, float lt, int t) {
        const float rl = 1.0f / lt;
        u16* lb = smem + w * 2304;
#pragma unroll
        for (int i = 0; i < 8; i++) {
            const int d = ((2 * i) & 3) + 8 * ((2 * i) >> 2) + (hi ? 4 : 0);
            *(unsigned*)&lb[l31 * 72 + d]      = cvtpk(a0[2 * i] * rl, a0[2 * i + 1] * rl);
            *(unsigned*)&lb[l31 * 72 + 32 + d] = cvtpk(a1[2 * i] * rl, a1[2 * i + 1] * rl);
        }
        asm volatile("s_waitcnt lgkmcnt(0)" ::: "memory");
#pragma unroll
        for (int i = 0; i < 4; i++) {
            const int qq = i * 8 + (lane >> 3), dd = (lane & 7) * 8;
            *(u16x8*)(o + (bS + t * 32 + qq) * 1024 + h * 64 + dd) = *(const u16x8*)&lb[qq * 72 + dd];
        }
    };
    if (par == 0) epi(a1lo, a1hi, l1t, t1);
    else          epi(a2lo, a2hi, l2t, t2);
}

// ---------------- launcher ----------------
extern "C" void kernel_launch(void* const* d_in, const int* in_sizes, int n_in,
                              void* d_out, int out_size, void* d_ws, size_t ws_size,
                              hipStream_t stream) {
    const float* x     = (const float*)d_in[0];
    const float* gamma = (const float*)d_in[1];
    const float* Wq    = (const float*)d_in[2];
    const float* Wkv   = (const float*)d_in[3];
    const float* Wo    = (const float*)d_in[4];
    float* out = (float*)d_out;
    char* ws = (char*)d_ws;

    u16* Wq_t  = (u16*)(ws + 0);             // 2 MB
    u16* Wo_t  = (u16*)(ws + (2u << 20));    // 2 MB
    u16* Wkv_t = (u16*)(ws + (4u << 20));    // 256 KB
    u16* xn    = (u16*)(ws + 4456448u);      // 8 MB
    u16* xb    = (u16*)(ws + 12845056u);     // 8 MB (free after kv-gemm; reused for kmax2)
    u16* qb    = (u16*)(ws + 21233664u);     // 8 MB
    u16* kb    = (u16*)(ws + 29622272u);     // 512 KB
    u16* vtb   = (u16*)(ws + 30146560u);     // 512 KB
    u16* attb  = (u16*)(ws + 30670848u);     // 8 MB
    unsigned* kmax2 = (unsigned*)xb;         // 8 B, written after xb's last use

    const dim3 tb(32, 8);
    const float qscale = 0.125f * 1.44269504f;   // SCALE * log2(e) folded into Wq
    transpose_cast<<<dim3(32, 32), tb, 0, stream>>>(Wq,  Wq_t,  1024, 1024, qscale);
    transpose_cast<<<dim3(32, 4),  tb, 0, stream>>>(Wkv, Wkv_t, 1024, 128, 1.0f);
    transpose_cast<<<dim3(32, 32), tb, 0, stream>>>(Wo,  Wo_t,  1024, 1024, 1.0f);

    ln_cast<<<4096, 256, 0, stream>>>(x, gamma, xn, xb);

    gemm_bt<128, 128, 0><<<dim3(32, 8), 256, 0, stream>>>(xn, Wq_t, qb, nullptr, nullptr, 4096, 1024, 1024);
    gemm_bt<64, 64, 2><<<dim3(64, 2), 256, 0, stream>>>(xb, Wkv_t, kb, nullptr, vtb, 4096, 128, 1024);
    hipMemsetAsync(kmax2, 0, 8, stream);
    kmax_kernel<<<64, 256, 0, stream>>>(kb, kmax2);
    attn_fwd<<<512, 256, 0, stream>>>(qb, kb, vtb, kmax2, attb);
    gemm_bt<128, 128, 1><<<dim3(32, 8), 256, 0, stream>>>(attb, Wo_t, nullptr, out, nullptr, 4096, 1024, 1024);
}

// Round 8
// 104.048 us; speedup vs baseline: 1.4582x; 1.0119x over previous
//
#include <hip/hip_runtime.h>

typedef unsigned short u16;
typedef __attribute__((ext_vector_type(8))) u16    u16x8;
typedef __attribute__((ext_vector_type(4))) u16    u16x4;
typedef __attribute__((ext_vector_type(2))) unsigned u32x2;
typedef __attribute__((ext_vector_type(8))) __bf16 bf16x8;
typedef __attribute__((ext_vector_type(4))) float  f32x4;
typedef __attribute__((ext_vector_type(16))) float f32x16;

__device__ __forceinline__ u16 f2bf(float f) {
    unsigned u = __float_as_uint(f);
    u += 0x7fffu + ((u >> 16) & 1u);   // RNE
    return (u16)(u >> 16);
}
__device__ __forceinline__ bf16x8 ldbf8(const u16* p) {
    return __builtin_bit_cast(bf16x8, *(const u16x8*)p);
}
__device__ __forceinline__ f32x4 mfma16(bf16x8 a, bf16x8 b, f32x4 c) {
    return __builtin_amdgcn_mfma_f32_16x16x32_bf16(a, b, c, 0, 0, 0);
}
__device__ __forceinline__ f32x16 mfma32x(bf16x8 a, bf16x8 b, f32x16 c) {
    return __builtin_amdgcn_mfma_f32_32x32x16_bf16(a, b, c, 0, 0, 0);
}
__device__ __forceinline__ float exp2a(float x) {
    float r; asm("v_exp_f32 %0, %1" : "=v"(r) : "v"(x)); return r;
}
__device__ __forceinline__ unsigned cvtpk(float lo, float hiv) {
    unsigned r; asm("v_cvt_pk_bf16_f32 %0, %1, %2" : "=v"(r) : "v"(lo), "v"(hiv)); return r;
}
__device__ __forceinline__ u32x2 permswap2(unsigned a, unsigned b) {
    return __builtin_amdgcn_permlane32_swap(a, b, false, false);
}
__device__ __forceinline__ float combine_sum(float x) {   // x + partner-half x (orientation-robust)
    u32x2 pr = permswap2(__float_as_uint(x), __float_as_uint(x));
    return __uint_as_float(pr[0]) + __uint_as_float(pr[1]);
}
__device__ __forceinline__ bf16x8 pack4(unsigned a, unsigned b, unsigned c, unsigned d) {
    union { unsigned u[4]; bf16x8 v; } t; t.u[0] = a; t.u[1] = b; t.u[2] = c; t.u[3] = d; return t.v;
}

// ---------------- weight transpose + cast:  Wt[n][k] = bf16(W[k][n] * scale) ----------------
__global__ void transpose_cast(const float* __restrict__ W, u16* __restrict__ Wt, int K, int N, float scale) {
    __shared__ float tile[32][33];
    int kb = blockIdx.x * 32, nb = blockIdx.y * 32;
    int tx = threadIdx.x, ty = threadIdx.y;          // (32, 8)
#pragma unroll
    for (int i = 0; i < 32; i += 8)
        tile[ty + i][tx] = W[(size_t)(kb + ty + i) * N + nb + tx];
    __syncthreads();
#pragma unroll
    for (int i = 0; i < 32; i += 8)
        Wt[(size_t)(nb + ty + i) * K + kb + tx] = f2bf(tile[tx][ty + i] * scale);
}

// ---------------- LayerNorm + cast: xn = bf16(LN(x)*gamma), xb = bf16(x) ----------------
__global__ __launch_bounds__(256) void ln_cast(const float* __restrict__ x, const float* __restrict__ gamma,
                                               u16* __restrict__ xn, u16* __restrict__ xb) {
    const int row = blockIdx.x;          // 4096 rows of 1024
    const int t = threadIdx.x;           // 256 threads, 4 floats each
    const float4 v = ((const float4*)(x + (size_t)row * 1024))[t];
    float s  = v.x + v.y + v.z + v.w;
    float s2 = v.x * v.x + v.y * v.y + v.z * v.z + v.w * v.w;
#pragma unroll
    for (int off = 32; off; off >>= 1) { s += __shfl_down(s, off); s2 += __shfl_down(s2, off); }
    __shared__ float red[2][4];
    const int w = t >> 6, lane = t & 63;
    if (lane == 0) { red[0][w] = s; red[1][w] = s2; }
    __syncthreads();
    s  = red[0][0] + red[0][1] + red[0][2] + red[0][3];
    s2 = red[1][0] + red[1][1] + red[1][2] + red[1][3];
    const float mu  = s * (1.0f / 1024.0f);
    const float var = s2 * (1.0f / 1024.0f) - mu * mu;
    const float rs  = rsqrtf(var + 1e-5f);
    const float4 g = ((const float4*)gamma)[t];
    u16x4 on, ob;
    on.x = f2bf((v.x - mu) * rs * g.x); on.y = f2bf((v.y - mu) * rs * g.y);
    on.z = f2bf((v.z - mu) * rs * g.z); on.w = f2bf((v.w - mu) * rs * g.w);
    ob.x = f2bf(v.x); ob.y = f2bf(v.y); ob.z = f2bf(v.z); ob.w = f2bf(v.w);
    ((u16x4*)(xn + (size_t)row * 1024))[t] = on;
    ((u16x4*)(xb + (size_t)row * 1024))[t] = ob;
}

// ---------------- GEMM: C[M,N] = A[M,K] @ Bt[N,K]^T (bf16 in, f32 acc) ----------------
template<int BM, int BN, int EPI>
__global__ __launch_bounds__(256) void gemm_bt(const u16* __restrict__ A, const u16* __restrict__ Bt,
                                               u16* __restrict__ Cb, float* __restrict__ Cf,
                                               u16* __restrict__ Cv, int M, int N, int K) {
    constexpr int WM = BM / 2, WN = BN / 2, FM = WM / 16, FN = WN / 16;
    constexpr int CHA = BM * 4, CH = (BM + BN) * 4, ITERS = CH / 256;  // 16B chunks, BK=32
    __shared__ __align__(16) u16 lds[2][(BM + BN) * 32];
    const int tid = threadIdx.x;
    const int m0 = blockIdx.x * BM, n0 = blockIdx.y * BN;
    const int w = tid >> 6, lane = tid & 63, cl = lane & 15, kg = lane >> 4;
    const int wr = w >> 1, wc = w & 1;

    auto stage = [&](int buf, int k0) {
#pragma unroll
        for (int it = 0; it < ITERS; ++it) {
            int c = it * 256 + tid;
            const u16* g;
            if (c < CHA) { int r = c >> 2, cc = c & 3; g = A  + (size_t)(m0 + r) * K + k0 + cc * 8; }
            else { int c2 = c - CHA; int r = c2 >> 2, cc = c2 & 3; g = Bt + (size_t)(n0 + r) * K + k0 + cc * 8; }
            __builtin_amdgcn_global_load_lds(
                (const __attribute__((address_space(1))) unsigned int*)g,
                (__attribute__((address_space(3))) unsigned int*)&lds[buf][c * 8], 16, 0, 0);
        }
    };

    const f32x4 zero = {0.f, 0.f, 0.f, 0.f};
    f32x4 acc[FM][FN];
#pragma unroll
    for (int m = 0; m < FM; m++)
#pragma unroll
        for (int n = 0; n < FN; n++) acc[m][n] = zero;

    const int KT = K / 32;
    stage(0, 0);
    for (int t = 0; t < KT; ++t) {
        __syncthreads();
        if (t + 1 < KT) stage((t + 1) & 1, (t + 1) * 32);
        const u16* As = &lds[t & 1][0];
        const u16* Bs = &lds[t & 1][BM * 32];
        bf16x8 af[FM], bfr[FN];
#pragma unroll
        for (int m = 0; m < FM; m++) af[m]  = ldbf8(As + (wr * WM + m * 16 + cl) * 32 + kg * 8);
#pragma unroll
        for (int n = 0; n < FN; n++) bfr[n] = ldbf8(Bs + (wc * WN + n * 16 + cl) * 32 + kg * 8);
#pragma unroll
        for (int m = 0; m < FM; m++)
#pragma unroll
            for (int n = 0; n < FN; n++) acc[m][n] = mfma16(af[m], bfr[n], acc[m][n]);
    }

#pragma unroll
    for (int m = 0; m < FM; m++)
#pragma unroll
        for (int n = 0; n < FN; n++)
#pragma unroll
            for (int r = 0; r < 4; r++) {
                const int row = m0 + wr * WM + m * 16 + kg * 4 + r;
                const int col = n0 + wc * WN + n * 16 + cl;
                const float v = acc[m][n][r];
                if constexpr (EPI == 0) Cb[(size_t)row * N + col] = f2bf(v);
                else if constexpr (EPI == 1) Cf[(size_t)row * N + col] = v;
                else {
                    if (col < 64) Cb[(size_t)row * 64 + col] = f2bf(v);
                    else { int bb = row >> 11, s = row & 2047;
                           Cv[((size_t)bb * 64 + (col - 64)) * 2048 + s] = f2bf(v); }
                }
            }
}

// ---------------- kmax partials: kpart[bid] = max over 64 rows of ||k_row||^2 (plain store) ------
__global__ __launch_bounds__(256) void kmax_kernel(const u16* __restrict__ kb, float* __restrict__ kpart) {
    const int b = blockIdx.x >> 5, blk = blockIdx.x & 31;    // 64 rows per block
    const int tid = threadIdx.x;
    const int r = blk * 64 + (tid >> 2), c4 = tid & 3;       // 4 threads/row, 16 elems each
    const u16* kp = kb + ((size_t)b * 2048 + r) * 64 + c4 * 16;
    float s2 = 0.f;
#pragma unroll
    for (int i = 0; i < 2; i++) {
        u16x8 v = ((const u16x8*)kp)[i];
#pragma unroll
        for (int j = 0; j < 8; j++) {
            const float f = __uint_as_float(((unsigned)v[j]) << 16);
            s2 = fmaf(f, f, s2);
        }
    }
    s2 += __shfl_xor(s2, 1); s2 += __shfl_xor(s2, 2);        // row sum
    float mx = s2;
#pragma unroll
    for (int off = 4; off < 64; off <<= 1) mx = fmaxf(mx, __shfl_xor(mx, off));
    __shared__ float red[4];
    if ((tid & 63) == 0) red[tid >> 6] = mx;
    __syncthreads();
    if (tid == 0)
        kpart[blockIdx.x] = fmaxf(fmaxf(red[0], red[1]), fmaxf(red[2], red[3]));
}

// ---------------- causal flash attention, MQA, Dh=64, balanced pairs + kv-parity split ----------
// Block = (b,h,p): 4 waves = (pair pw) x (kv-parity par). Wave handles q-tiles t1=2p+pw and
// t2=63-t1 over kv tiles jt≡par(2), jt≤t. One shared kv sweep stages 2 tiles/iter into LDS.
// Fixed-bound softmax (m_i = ||q_i||*kmax): parity merge = plain add in LDS.
__global__ __launch_bounds__(256, 2) void attn_fwd(const u16* __restrict__ q, const u16* __restrict__ k,
                                                   const u16* __restrict__ vt, const float* __restrict__ kpart,
                                                   u16* __restrict__ o) {
    constexpr int S = 2048;
    const int bid = blockIdx.x;
    const int p = (bid < 256) ? (bid >> 5) : (15 - ((bid - 256) >> 5));  // pair long+short sweeps per CU
    const int bh = bid & 31;
    const int h = bh & 15, b = bh >> 4;
    const int tid = threadIdx.x, w = tid >> 6, lane = tid & 63;
    const int pw = w & 1, par = w >> 1;
    const int l31 = lane & 31;
    const bool hi = (lane & 32) != 0;
    const int hi1 = hi ? 1 : 0, hi8 = hi ? 8 : 0;
    const int t1 = 2 * p + pw, t2 = 63 - t1;
    const int iters = 32 - p;                    // kv tiles 0..63-2p, two per iteration
    const size_t bS = (size_t)b * S;

    // smem 36864B: stage region (kls 4x4KB + vls 4x5KB = 36KB) ∪ merge (4x64x36 f32) ∪ epi (18KB)
    __shared__ __align__(16) u16 smem[18432];

    auto stageK = [&](int jt, int buf, int tl) {             // one 32x64 K tile, swizzled source
        const int r = tid >> 3, c = tid & 7;
        const u16* gp = k + (bS + jt * 32 + r) * 64 + ((c ^ (r & 7)) * 8);
        __builtin_amdgcn_global_load_lds(
            (const __attribute__((address_space(1))) unsigned int*)gp,
            (__attribute__((address_space(3))) unsigned int*)(smem + (buf * 2 + tl) * 2048 + tid * 8), 16, 0, 0);
    };
    auto loadV = [&](int jt) -> u16x8 {                      // V^T tile [64 d][32 kv]
        const int rv = tid >> 2, c4 = tid & 3;
        return *(const u16x8*)(vt + ((size_t)b * 64 + rv) * S + jt * 32 + c4 * 8);
    };
    auto writeV = [&](int buf, int tl, u16x8 v) {
        const int rv = tid >> 2, c4 = tid & 3;
        *(u16x8*)(smem + 8192 + (buf * 2 + tl) * 2560 + rv * 40 + c4 * 8) = v;
    };

    // reduce 32 kmax partials for this batch (written by kmax_kernel; no init/atomics needed)
    float km = kpart[(b << 5) + l31];
#pragma unroll
    for (int off = 1; off < 32; off <<= 1) km = fmaxf(km, __shfl_xor(km, off));
    const float kmaxb = sqrtf(km);

    bf16x8 qf1[4], qf2[4];
    float mB1, mB2;
    auto qload = [&](int t, bf16x8 (&qf)[4]) -> float {
        const u16* qp = q + (bS + t * 32 + l31) * 1024 + h * 64 + hi8;
        float qn2 = 0.f;
#pragma unroll
        for (int sub = 0; sub < 4; sub++) {
            qf[sub] = ldbf8(qp + sub * 16);
            const u16x8 uv = __builtin_bit_cast(u16x8, qf[sub]);
#pragma unroll
            for (int j = 0; j < 8; j++) {
                const float v = __uint_as_float(((unsigned)uv[j]) << 16);
                qn2 = fmaf(v, v, qn2);
            }
        }
        return sqrtf(combine_sum(qn2)) * kmaxb;
    };
    mB1 = qload(t1, qf1);
    mB2 = qload(t2, qf2);

    f32x16 a1lo, a1hi, a2lo, a2hi;               // O^T accumulators for q1, q2
#pragma unroll
    for (int r = 0; r < 16; r++) { a1lo[r] = 0.f; a1hi[r] = 0.f; a2lo[r] = 0.f; a2hi[r] = 0.f; }
    float l1 = 0.f, l2 = 0.f;

    auto process = [&](const bf16x8 (&qf)[4], const bf16x8 (&kf)[4],
                       const bf16x8& vf00, const bf16x8& vf01, const bf16x8& vf10, const bf16x8& vf11,
                       f32x16& a0, f32x16& a1, float& lr, float mB, bool diag) {
        f32x16 s;
#pragma unroll
        for (int r = 0; r < 16; r++) s[r] = 0.f;
#pragma unroll
        for (int sub = 0; sub < 4; sub++) s = mfma32x(kf[sub], qf[sub], s);
        if (diag) {
#pragma unroll
            for (int r = 0; r < 16; r++) {
                const int kvl = (r & 3) + 8 * (r >> 2) + (hi ? 4 : 0);
                if (kvl > l31) s[r] = -1e30f;
            }
        }
        float p0 = 0.f, p1 = 0.f;
#pragma unroll
        for (int r = 0; r < 16; r += 2) {
            const float ea = exp2a(s[r] - mB);
            const float eb = exp2a(s[r + 1] - mB);
            s[r] = ea; s[r + 1] = eb;
            p0 += ea; p1 += eb;
        }
        lr += p0 + p1;
        unsigned w0 = cvtpk(s[0], s[1]),  w1 = cvtpk(s[2], s[3]);
        unsigned w2 = cvtpk(s[4], s[5]),  w3 = cvtpk(s[6], s[7]);
        u32x2 r02 = permswap2(w0, w2), r13 = permswap2(w1, w3);
        bf16x8 pf0 = pack4(r02[0], r13[0], r02[1], r13[1]);
        unsigned y0 = cvtpk(s[8], s[9]),   y1 = cvtpk(s[10], s[11]);
        unsigned y2 = cvtpk(s[12], s[13]), y3 = cvtpk(s[14], s[15]);
        u32x2 t02 = permswap2(y0, y2), t13 = permswap2(y1, y3);
        bf16x8 pf1 = pack4(t02[0], t13[0], t02[1], t13[1]);
        a0 = mfma32x(vf00, pf0, a0);
        a0 = mfma32x(vf01, pf1, a0);
        a1 = mfma32x(vf10, pf0, a1);
        a1 = mfma32x(vf11, pf1, a1);
    };

    // ---- shared kv sweep: 2 tiles/iter, double-buffered; 1 __syncthreads per iter ----
    stageK(0, 0, 0); stageK(1, 0, 1);
    u16x8 v0 = loadV(0), v1 = loadV(1);
    for (int i = 0; i < iters; i++) {
        const int buf = i & 1;
        writeV(buf, 0, v0); writeV(buf, 1, v1);
        __syncthreads();                         // drains vmcnt (K pair i) + lgkm (V writes), then barrier
        if (i + 1 < iters) {
            stageK(2 * i + 2, buf ^ 1, 0); stageK(2 * i + 3, buf ^ 1, 1);
            v0 = loadV(2 * i + 2); v1 = loadV(2 * i + 3);
        }
        const int jt = 2 * i + par;
        if (jt <= t2) {
            const u16* kcur = smem + (buf * 2 + par) * 2048;
            const u16* vcur = smem + 8192 + (buf * 2 + par) * 2560;
            bf16x8 kf[4];
#pragma unroll
            for (int sub = 0; sub < 4; sub++)
                kf[sub] = ldbf8(kcur + l31 * 64 + (((sub * 2 + hi1) ^ (l31 & 7)) * 8));
            const bf16x8 vf00 = ldbf8(vcur + l31 * 40 + hi8);
            const bf16x8 vf01 = ldbf8(vcur + l31 * 40 + 16 + hi8);
            const bf16x8 vf10 = ldbf8(vcur + (32 + l31) * 40 + hi8);
            const bf16x8 vf11 = ldbf8(vcur + (32 + l31) * 40 + 16 + hi8);
            if (jt <= t1) process(qf1, kf, vf00, vf01, vf10, vf11, a1lo, a1hi, l1, mB1, jt == t1);
            process(qf2, kf, vf00, vf01, vf10, vf11, a2lo, a2hi, l2, mB2, jt == t2);
        }
    }
    float l1t = combine_sum(l1), l2t = combine_sum(l2);

    // ---- parity merge (plain add; fixed bound -> no rescale). Slot[pw][0]=q1 from par1, [1]=q2 from par0.
    float* fm = (float*)smem;
    __syncthreads();                             // all stage-buffer reads done; safe to alias
    {
        float* dst = fm + (((pw * 2) + (par ? 0 : 1)) * 64 + lane) * 36;
        if (par) { *(f32x16*)dst = a1lo; *(f32x16*)(dst + 16) = a1hi; dst[32] = l1t; }
        else     { *(f32x16*)dst = a2lo; *(f32x16*)(dst + 16) = a2hi; dst[32] = l2t; }
    }
    __syncthreads();
    {
        const float* src = fm + (((pw * 2) + (par ? 1 : 0)) * 64 + lane) * 36;
        const f32x16 s0 = *(const f32x16*)src;
        const f32x16 s1 = *(const f32x16*)(src + 16);
        if (par) {
#pragma unroll
            for (int r = 0; r < 16; r++) { a2lo[r] += s0[r]; a2hi[r] += s1[r]; }
            l2t += src[32];
        } else {
#pragma unroll
            for (int r = 0; r < 16; r++) { a1lo[r] += s0[r]; a1hi[r] += s1[r]; }
            l1t += src[32];
        }
    }
    __syncthreads();                             // merge reads done; safe to alias for epilogue

    // ---- epilogue: wave par=0 owns q1, par=1 owns q2. O^T -> LDS [32q][72] -> coalesced ----
    auto epi = [&](const f32x16& a0, const f32x16& a1, float lt, int t) {
        const float rl = 1.0f / lt;
        u16* lb = smem + w * 2304;
#pragma unroll
        for (int i = 0; i < 8; i++) {
            const int d = ((2 * i) & 3) + 8 * ((2 * i) >> 2) + (hi ? 4 : 0);
            *(unsigned*)&lb[l31 * 72 + d]      = cvtpk(a0[2 * i] * rl, a0[2 * i + 1] * rl);
            *(unsigned*)&lb[l31 * 72 + 32 + d] = cvtpk(a1[2 * i] * rl, a1[2 * i + 1] * rl);
        }
        asm volatile("s_waitcnt lgkmcnt(0)" ::: "memory");
#pragma unroll
        for (int i = 0; i < 4; i++) {
            const int qq = i * 8 + (lane >> 3), dd = (lane & 7) * 8;
            *(u16x8*)(o + (bS + t * 32 + qq) * 1024 + h * 64 + dd) = *(const u16x8*)&lb[qq * 72 + dd];
        }
    };
    if (par == 0) epi(a1lo, a1hi, l1t, t1);
    else          epi(a2lo, a2hi, l2t, t2);
}

// ---------------- launcher ----------------
extern "C" void kernel_launch(void* const* d_in, const int* in_sizes, int n_in,
                              void* d_out, int out_size, void* d_ws, size_t ws_size,
                              hipStream_t stream) {
    const float* x     = (const float*)d_in[0];
    const float* gamma = (const float*)d_in[1];
    const float* Wq    = (const float*)d_in[2];
    const float* Wkv   = (const float*)d_in[3];
    const float* Wo    = (const float*)d_in[4];
    float* out = (float*)d_out;
    char* ws = (char*)d_ws;

    u16* Wq_t  = (u16*)(ws + 0);             // 2 MB
    u16* Wo_t  = (u16*)(ws + (2u << 20));    // 2 MB
    u16* Wkv_t = (u16*)(ws + (4u << 20));    // 256 KB
    u16* xn    = (u16*)(ws + 4456448u);      // 8 MB
    u16* xb    = (u16*)(ws + 12845056u);     // 8 MB (free after kv-gemm; reused for kpart)
    u16* qb    = (u16*)(ws + 21233664u);     // 8 MB
    u16* kb    = (u16*)(ws + 29622272u);     // 512 KB
    u16* vtb   = (u16*)(ws + 30146560u);     // 512 KB
    u16* attb  = (u16*)(ws + 30670848u);     // 8 MB
    float* kpart = (float*)xb;               // 64 floats, written after xb's last use

    const dim3 tb(32, 8);
    const float qscale = 0.125f * 1.44269504f;   // SCALE * log2(e) folded into Wq
    transpose_cast<<<dim3(32, 32), tb, 0, stream>>>(Wq,  Wq_t,  1024, 1024, qscale);
    transpose_cast<<<dim3(32, 4),  tb, 0, stream>>>(Wkv, Wkv_t, 1024, 128, 1.0f);
    transpose_cast<<<dim3(32, 32), tb, 0, stream>>>(Wo,  Wo_t,  1024, 1024, 1.0f);

    ln_cast<<<4096, 256, 0, stream>>>(x, gamma, xn, xb);

    gemm_bt<128, 128, 0><<<dim3(32, 8), 256, 0, stream>>>(xn, Wq_t, qb, nullptr, nullptr, 4096, 1024, 1024);
    gemm_bt<64, 64, 2><<<dim3(64, 2), 256, 0, stream>>>(xb, Wkv_t, kb, nullptr, vtb, 4096, 128, 1024);
    kmax_kernel<<<64, 256, 0, stream>>>(kb, kpart);
    attn_fwd<<<512, 256, 0, stream>>>(qb, kb, vtb, kpart, attb);
    gemm_bt<128, 128, 1><<<dim3(32, 8), 256, 0, stream>>>(attb, Wo_t, nullptr, out, nullptr, 4096, 1024, 1024);
}

// Round 9
// 94.415 us; speedup vs baseline: 1.6070x; 1.1020x over previous
//
#include <hip/hip_runtime.h>

typedef unsigned short u16;
typedef __attribute__((ext_vector_type(8))) u16    u16x8;
typedef __attribute__((ext_vector_type(4))) u16    u16x4;
typedef __attribute__((ext_vector_type(2))) unsigned u32x2;
typedef __attribute__((ext_vector_type(8))) __bf16 bf16x8;
typedef __attribute__((ext_vector_type(4))) float  f32x4;
typedef __attribute__((ext_vector_type(16))) float f32x16;

__device__ __forceinline__ u16 f2bf(float f) {
    unsigned u = __float_as_uint(f);
    u += 0x7fffu + ((u >> 16) & 1u);   // RNE
    return (u16)(u >> 16);
}
__device__ __forceinline__ bf16x8 ldbf8(const u16* p) {
    return __builtin_bit_cast(bf16x8, *(const u16x8*)p);
}
__device__ __forceinline__ f32x4 mfma16(bf16x8 a, bf16x8 b, f32x4 c) {
    return __builtin_amdgcn_mfma_f32_16x16x32_bf16(a, b, c, 0, 0, 0);
}
__device__ __forceinline__ f32x16 mfma32x(bf16x8 a, bf16x8 b, f32x16 c) {
    return __builtin_amdgcn_mfma_f32_32x32x16_bf16(a, b, c, 0, 0, 0);
}
__device__ __forceinline__ float exp2a(float x) {
    float r; asm("v_exp_f32 %0, %1" : "=v"(r) : "v"(x)); return r;
}
__device__ __forceinline__ unsigned cvtpk(float lo, float hiv) {
    unsigned r; asm("v_cvt_pk_bf16_f32 %0, %1, %2" : "=v"(r) : "v"(lo), "v"(hiv)); return r;
}
__device__ __forceinline__ u32x2 permswap2(unsigned a, unsigned b) {
    return __builtin_amdgcn_permlane32_swap(a, b, false, false);
}
__device__ __forceinline__ float combine_sum(float x) {   // x + partner-half x (orientation-robust)
    u32x2 pr = permswap2(__float_as_uint(x), __float_as_uint(x));
    return __uint_as_float(pr[0]) + __uint_as_float(pr[1]);
}
__device__ __forceinline__ bf16x8 pack4(unsigned a, unsigned b, unsigned c, unsigned d) {
    union { unsigned u[4]; bf16x8 v; } t; t.u[0] = a; t.u[1] = b; t.u[2] = c; t.u[3] = d; return t.v;
}

// ---------------- all weight transposes in one launch: Wt[n][k] = bf16(W[k][n]*scale) ----------
__global__ void transpose_cast_all(const float* __restrict__ Wq, const float* __restrict__ Wkv,
                                   const float* __restrict__ Wo, u16* __restrict__ Wq_t,
                                   u16* __restrict__ Wkv_t, u16* __restrict__ Wo_t, float qscale) {
    __shared__ float tile[32][33];
    int by = blockIdx.y;
    const float* W; u16* Wt; int N; float scale;
    if (by < 32)      { W = Wq;  Wt = Wq_t;  N = 1024; scale = qscale; }
    else if (by < 36) { W = Wkv; Wt = Wkv_t; N = 128;  by -= 32; scale = 1.0f; }
    else              { W = Wo;  Wt = Wo_t;  N = 1024; by -= 36; scale = 1.0f; }
    const int K = 1024;
    int kb = blockIdx.x * 32, nb = by * 32;
    int tx = threadIdx.x, ty = threadIdx.y;          // (32, 8)
#pragma unroll
    for (int i = 0; i < 32; i += 8)
        tile[ty + i][tx] = W[(size_t)(kb + ty + i) * N + nb + tx];
    __syncthreads();
#pragma unroll
    for (int i = 0; i < 32; i += 8)
        Wt[(size_t)(nb + ty + i) * K + kb + tx] = f2bf(tile[tx][ty + i] * scale);
}

// ---------------- LayerNorm + cast: xn = bf16(LN(x)*gamma), xb = bf16(x) ----------------
__global__ __launch_bounds__(256) void ln_cast(const float* __restrict__ x, const float* __restrict__ gamma,
                                               u16* __restrict__ xn, u16* __restrict__ xb) {
    const int row = blockIdx.x;          // 4096 rows of 1024
    const int t = threadIdx.x;           // 256 threads, 4 floats each
    const float4 v = ((const float4*)(x + (size_t)row * 1024))[t];
    float s  = v.x + v.y + v.z + v.w;
    float s2 = v.x * v.x + v.y * v.y + v.z * v.z + v.w * v.w;
#pragma unroll
    for (int off = 32; off; off >>= 1) { s += __shfl_down(s, off); s2 += __shfl_down(s2, off); }
    __shared__ float red[2][4];
    const int w = t >> 6, lane = t & 63;
    if (lane == 0) { red[0][w] = s; red[1][w] = s2; }
    __syncthreads();
    s  = red[0][0] + red[0][1] + red[0][2] + red[0][3];
    s2 = red[1][0] + red[1][1] + red[1][2] + red[1][3];
    const float mu  = s * (1.0f / 1024.0f);
    const float var = s2 * (1.0f / 1024.0f) - mu * mu;
    const float rs  = rsqrtf(var + 1e-5f);
    const float4 g = ((const float4*)gamma)[t];
    u16x4 on, ob;
    on.x = f2bf((v.x - mu) * rs * g.x); on.y = f2bf((v.y - mu) * rs * g.y);
    on.z = f2bf((v.z - mu) * rs * g.z); on.w = f2bf((v.w - mu) * rs * g.w);
    ob.x = f2bf(v.x); ob.y = f2bf(v.y); ob.z = f2bf(v.z); ob.w = f2bf(v.w);
    ((u16x4*)(xn + (size_t)row * 1024))[t] = on;
    ((u16x4*)(xb + (size_t)row * 1024))[t] = ob;
}

// ---------------- GEMM: C[M,N] = A[M,K] @ Bt[N,K]^T (bf16 in, f32 acc) ----------------
template<int BM, int BN, int EPI>
__global__ __launch_bounds__(256, 2) void gemm_bt(const u16* __restrict__ A, const u16* __restrict__ Bt,
                                                  u16* __restrict__ Cb, float* __restrict__ Cf,
                                                  u16* __restrict__ Cv, int M, int N, int K) {
    constexpr int WM = BM / 2, WN = BN / 2, FM = WM / 16, FN = WN / 16;
    constexpr int CHA = BM * 4, CH = (BM + BN) * 4, ITERS = CH / 256;  // 16B chunks, BK=32
    __shared__ __align__(16) u16 lds[2][(BM + BN) * 32];
    const int tid = threadIdx.x;
    const int m0 = blockIdx.x * BM, n0 = blockIdx.y * BN;
    const int w = tid >> 6, lane = tid & 63, cl = lane & 15, kg = lane >> 4;
    const int wr = w >> 1, wc = w & 1;

    auto stage = [&](int buf, int k0) {
#pragma unroll
        for (int it = 0; it < ITERS; ++it) {
            int c = it * 256 + tid;
            const u16* g;
            if (c < CHA) { int r = c >> 2, cc = c & 3; g = A  + (size_t)(m0 + r) * K + k0 + cc * 8; }
            else { int c2 = c - CHA; int r = c2 >> 2, cc = c2 & 3; g = Bt + (size_t)(n0 + r) * K + k0 + cc * 8; }
            __builtin_amdgcn_global_load_lds(
                (const __attribute__((address_space(1))) unsigned int*)g,
                (__attribute__((address_space(3))) unsigned int*)&lds[buf][c * 8], 16, 0, 0);
        }
    };

    const f32x4 zero = {0.f, 0.f, 0.f, 0.f};
    f32x4 acc[FM][FN];
#pragma unroll
    for (int m = 0; m < FM; m++)
#pragma unroll
        for (int n = 0; n < FN; n++) acc[m][n] = zero;

    const int KT = K / 32;
    stage(0, 0);
    for (int t = 0; t < KT; ++t) {
        __syncthreads();
        if (t + 1 < KT) stage((t + 1) & 1, (t + 1) * 32);
        const u16* As = &lds[t & 1][0];
        const u16* Bs = &lds[t & 1][BM * 32];
        bf16x8 af[FM], bfr[FN];
#pragma unroll
        for (int m = 0; m < FM; m++) af[m]  = ldbf8(As + (wr * WM + m * 16 + cl) * 32 + kg * 8);
#pragma unroll
        for (int n = 0; n < FN; n++) bfr[n] = ldbf8(Bs + (wc * WN + n * 16 + cl) * 32 + kg * 8);
#pragma unroll
        for (int m = 0; m < FM; m++)
#pragma unroll
            for (int n = 0; n < FN; n++) acc[m][n] = mfma16(af[m], bfr[n], acc[m][n]);
    }

#pragma unroll
    for (int m = 0; m < FM; m++)
#pragma unroll
        for (int n = 0; n < FN; n++)
#pragma unroll
            for (int r = 0; r < 4; r++) {
                const int row = m0 + wr * WM + m * 16 + kg * 4 + r;
                const int col = n0 + wc * WN + n * 16 + cl;
                const float v = acc[m][n][r];
                if constexpr (EPI == 0) Cb[(size_t)row * N + col] = f2bf(v);
                else if constexpr (EPI == 1) Cf[(size_t)row * N + col] = v;
                else {
                    if (col < 64) Cb[(size_t)row * 64 + col] = f2bf(v);
                    else { int bb = row >> 11, s = row & 2047;
                           Cv[((size_t)bb * 64 + (col - 64)) * 2048 + s] = f2bf(v); }
                }
            }
}

// ---------------- kmax partials: kpart[bid] = max over 64 rows of ||k_row||^2 (plain store) ------
__global__ __launch_bounds__(256) void kmax_kernel(const u16* __restrict__ kb, float* __restrict__ kpart) {
    const int b = blockIdx.x >> 5, blk = blockIdx.x & 31;    // 64 rows per block
    const int tid = threadIdx.x;
    const int r = blk * 64 + (tid >> 2), c4 = tid & 3;       // 4 threads/row, 16 elems each
    const u16* kp = kb + ((size_t)b * 2048 + r) * 64 + c4 * 16;
    float s2 = 0.f;
#pragma unroll
    for (int i = 0; i < 2; i++) {
        u16x8 v = ((const u16x8*)kp)[i];
#pragma unroll
        for (int j = 0; j < 8; j++) {
            const float f = __uint_as_float(((unsigned)v[j]) << 16);
            s2 = fmaf(f, f, s2);
        }
    }
    s2 += __shfl_xor(s2, 1); s2 += __shfl_xor(s2, 2);        // row sum
    float mx = s2;
#pragma unroll
    for (int off = 4; off < 64; off <<= 1) mx = fmaxf(mx, __shfl_xor(mx, off));
    __shared__ float red[4];
    if ((tid & 63) == 0) red[tid >> 6] = mx;
    __syncthreads();
    if (tid == 0)
        kpart[blockIdx.x] = fmaxf(fmaxf(red[0], red[1]), fmaxf(red[2], red[3]));
}

// ---------------- causal flash attention, MQA, Dh=64, balanced pairs + kv-parity split ----------
// Block = (b,h,p): 4 waves = (pair pw) x (kv-parity par). Wave handles q-tiles t1=2p+pw and
// t2=63-t1 over kv tiles jt≡par(2), jt≤t. One shared kv sweep stages 2 tiles/iter into LDS.
// Fixed-bound softmax (m_i = ||q_i||*kmax): parity merge = plain add in LDS.
__global__ __launch_bounds__(256, 2) void attn_fwd(const u16* __restrict__ q, const u16* __restrict__ k,
                                                   const u16* __restrict__ vt, const float* __restrict__ kpart,
                                                   u16* __restrict__ o) {
    constexpr int S = 2048;
    const int bid = blockIdx.x;
    const int p = (bid < 256) ? (bid >> 5) : (15 - ((bid - 256) >> 5));  // pair long+short sweeps per CU
    const int bh = bid & 31;
    const int h = bh & 15, b = bh >> 4;
    const int tid = threadIdx.x, w = tid >> 6, lane = tid & 63;
    const int pw = w & 1, par = w >> 1;
    const int l31 = lane & 31;
    const bool hi = (lane & 32) != 0;
    const int hi1 = hi ? 1 : 0, hi8 = hi ? 8 : 0;
    const int t1 = 2 * p + pw, t2 = 63 - t1;
    const int iters = 32 - p;                    // kv tiles 0..63-2p, two per iteration
    const size_t bS = (size_t)b * S;

    // smem 36864B: stage region (kls 4x4KB + vls 4x5KB = 36KB) ∪ merge (4x64x36 f32) ∪ epi (18KB)
    __shared__ __align__(16) u16 smem[18432];

    auto stageK = [&](int jt, int buf, int tl) {             // one 32x64 K tile, swizzled source
        const int r = tid >> 3, c = tid & 7;
        const u16* gp = k + (bS + jt * 32 + r) * 64 + ((c ^ (r & 7)) * 8);
        __builtin_amdgcn_global_load_lds(
            (const __attribute__((address_space(1))) unsigned int*)gp,
            (__attribute__((address_space(3))) unsigned int*)(smem + (buf * 2 + tl) * 2048 + tid * 8), 16, 0, 0);
    };
    auto loadV = [&](int jt) -> u16x8 {                      // V^T tile [64 d][32 kv]
        const int rv = tid >> 2, c4 = tid & 3;
        return *(const u16x8*)(vt + ((size_t)b * 64 + rv) * S + jt * 32 + c4 * 8);
    };
    auto writeV = [&](int buf, int tl, u16x8 v) {
        const int rv = tid >> 2, c4 = tid & 3;
        *(u16x8*)(smem + 8192 + (buf * 2 + tl) * 2560 + rv * 40 + c4 * 8) = v;
    };

    // reduce 32 kmax partials for this batch (written by kmax_kernel; no init/atomics needed)
    float km = kpart[(b << 5) + l31];
#pragma unroll
    for (int off = 1; off < 32; off <<= 1) km = fmaxf(km, __shfl_xor(km, off));
    const float kmaxb = sqrtf(km);

    bf16x8 qf1[4], qf2[4];
    float mB1, mB2;
    auto qload = [&](int t, bf16x8 (&qf)[4]) -> float {
        const u16* qp = q + (bS + t * 32 + l31) * 1024 + h * 64 + hi8;
        float qn2 = 0.f;
#pragma unroll
        for (int sub = 0; sub < 4; sub++) {
            qf[sub] = ldbf8(qp + sub * 16);
            const u16x8 uv = __builtin_bit_cast(u16x8, qf[sub]);
#pragma unroll
            for (int j = 0; j < 8; j++) {
                const float v = __uint_as_float(((unsigned)uv[j]) << 16);
                qn2 = fmaf(v, v, qn2);
            }
        }
        return sqrtf(combine_sum(qn2)) * kmaxb;
    };
    mB1 = qload(t1, qf1);
    mB2 = qload(t2, qf2);

    f32x16 a1lo, a1hi, a2lo, a2hi;               // O^T accumulators for q1, q2
#pragma unroll
    for (int r = 0; r < 16; r++) { a1lo[r] = 0.f; a1hi[r] = 0.f; a2lo[r] = 0.f; a2hi[r] = 0.f; }
    float l1 = 0.f, l2 = 0.f;

    auto process = [&](const bf16x8 (&qf)[4], const bf16x8 (&kf)[4],
                       const bf16x8& vf00, const bf16x8& vf01, const bf16x8& vf10, const bf16x8& vf11,
                       f32x16& a0, f32x16& a1, float& lr, float mB, bool diag) {
        f32x16 s;
#pragma unroll
        for (int r = 0; r < 16; r++) s[r] = 0.f;
#pragma unroll
        for (int sub = 0; sub < 4; sub++) s = mfma32x(kf[sub], qf[sub], s);
        if (diag) {
#pragma unroll
            for (int r = 0; r < 16; r++) {
                const int kvl = (r & 3) + 8 * (r >> 2) + (hi ? 4 : 0);
                if (kvl > l31) s[r] = -1e30f;
            }
        }
        float p0 = 0.f, p1 = 0.f;
#pragma unroll
        for (int r = 0; r < 16; r += 2) {
            const float ea = exp2a(s[r] - mB);
            const float eb = exp2a(s[r + 1] - mB);
            s[r] = ea; s[r + 1] = eb;
            p0 += ea; p1 += eb;
        }
        lr += p0 + p1;
        unsigned w0 = cvtpk(s[0], s[1]),  w1 = cvtpk(s[2], s[3]);
        unsigned w2 = cvtpk(s[4], s[5]),  w3 = cvtpk(s[6], s[7]);
        u32x2 r02 = permswap2(w0, w2), r13 = permswap2(w1, w3);
        bf16x8 pf0 = pack4(r02[0], r13[0], r02[1], r13[1]);
        unsigned y0 = cvtpk(s[8], s[9]),   y1 = cvtpk(s[10], s[11]);
        unsigned y2 = cvtpk(s[12], s[13]), y3 = cvtpk(s[14], s[15]);
        u32x2 t02 = permswap2(y0, y2), t13 = permswap2(y1, y3);
        bf16x8 pf1 = pack4(t02[0], t13[0], t02[1], t13[1]);
        a0 = mfma32x(vf00, pf0, a0);
        a0 = mfma32x(vf01, pf1, a0);
        a1 = mfma32x(vf10, pf0, a1);
        a1 = mfma32x(vf11, pf1, a1);
    };

    // ---- shared kv sweep: 2 tiles/iter, double-buffered; 1 __syncthreads per iter ----
    stageK(0, 0, 0); stageK(1, 0, 1);
    u16x8 v0 = loadV(0), v1 = loadV(1);
    for (int i = 0; i < iters; i++) {
        const int buf = i & 1;
        writeV(buf, 0, v0); writeV(buf, 1, v1);
        __syncthreads();                         // drains vmcnt (K pair i) + lgkm (V writes), then barrier
        if (i + 1 < iters) {
            stageK(2 * i + 2, buf ^ 1, 0); stageK(2 * i + 3, buf ^ 1, 1);
            v0 = loadV(2 * i + 2); v1 = loadV(2 * i + 3);
        }
        const int jt = 2 * i + par;
        if (jt <= t2) {
            const u16* kcur = smem + (buf * 2 + par) * 2048;
            const u16* vcur = smem + 8192 + (buf * 2 + par) * 2560;
            bf16x8 kf[4];
#pragma unroll
            for (int sub = 0; sub < 4; sub++)
                kf[sub] = ldbf8(kcur + l31 * 64 + (((sub * 2 + hi1) ^ (l31 & 7)) * 8));
            const bf16x8 vf00 = ldbf8(vcur + l31 * 40 + hi8);
            const bf16x8 vf01 = ldbf8(vcur + l31 * 40 + 16 + hi8);
            const bf16x8 vf10 = ldbf8(vcur + (32 + l31) * 40 + hi8);
            const bf16x8 vf11 = ldbf8(vcur + (32 + l31) * 40 + 16 + hi8);
            if (jt <= t1) process(qf1, kf, vf00, vf01, vf10, vf11, a1lo, a1hi, l1, mB1, jt == t1);
            process(qf2, kf, vf00, vf01, vf10, vf11, a2lo, a2hi, l2, mB2, jt == t2);
        }
    }
    float l1t = combine_sum(l1), l2t = combine_sum(l2);

    // ---- parity merge (plain add; fixed bound -> no rescale). Slot[pw][0]=q1 from par1, [1]=q2 from par0.
    float* fm = (float*)smem;
    __syncthreads();                             // all stage-buffer reads done; safe to alias
    {
        float* dst = fm + (((pw * 2) + (par ? 0 : 1)) * 64 + lane) * 36;
        if (par) { *(f32x16*)dst = a1lo; *(f32x16*)(dst + 16) = a1hi; dst[32] = l1t; }
        else     { *(f32x16*)dst = a2lo; *(f32x16*)(dst + 16) = a2hi; dst[32] = l2t; }
    }
    __syncthreads();
    {
        const float* src = fm + (((pw * 2) + (par ? 1 : 0)) * 64 + lane) * 36;
        const f32x16 s0 = *(const f32x16*)src;
        const f32x16 s1 = *(const f32x16*)(src + 16);
        if (par) {
#pragma unroll
            for (int r = 0; r < 16; r++) { a2lo[r] += s0[r]; a2hi[r] += s1[r]; }
            l2t += src[32];
        } else {
#pragma unroll
            for (int r = 0; r < 16; r++) { a1lo[r] += s0[r]; a1hi[r] += s1[r]; }
            l1t += src[32];
        }
    }
    __syncthreads();                             // merge reads done; safe to alias for epilogue

    // ---- epilogue: wave par=0 owns q1, par=1 owns q2. O^T -> LDS [32q][72] -> coalesced ----
    auto epi = [&](const f32x16& a0, const f32x16& a1, float lt, int t) {
        const float rl = 1.0f / lt;
        u16* lb = smem + w * 2304;
#pragma unroll
        for (int i = 0; i < 8; i++) {
            const int d = ((2 * i) & 3) + 8 * ((2 * i) >> 2) + (hi ? 4 : 0);
            *(unsigned*)&lb[l31 * 72 + d]      = cvtpk(a0[2 * i] * rl, a0[2 * i + 1] * rl);
            *(unsigned*)&lb[l31 * 72 + 32 + d] = cvtpk(a1[2 * i] * rl, a1[2 * i + 1] * rl);
        }
        asm volatile("s_waitcnt lgkmcnt(0)" ::: "memory");
#pragma unroll
        for (int i = 0; i < 4; i++) {
            const int qq = i * 8 + (lane >> 3), dd = (lane & 7) * 8;
            *(u16x8*)(o + (bS + t * 32 + qq) * 1024 + h * 64 + dd) = *(const u16x8*)&lb[qq * 72 + dd];
        }
    };
    if (par == 0) epi(a1lo, a1hi, l1t, t1);
    else          epi(a2lo, a2hi, l2t, t2);
}

// ---------------- launcher ----------------
extern "C" void kernel_launch(void* const* d_in, const int* in_sizes, int n_in,
                              void* d_out, int out_size, void* d_ws, size_t ws_size,
                              hipStream_t stream) {
    const float* x     = (const float*)d_in[0];
    const float* gamma = (const float*)d_in[1];
    const float* Wq    = (const float*)d_in[2];
    const float* Wkv   = (const float*)d_in[3];
    const float* Wo    = (const float*)d_in[4];
    float* out = (float*)d_out;
    char* ws = (char*)d_ws;

    u16* Wq_t  = (u16*)(ws + 0);             // 2 MB
    u16* Wo_t  = (u16*)(ws + (2u << 20));    // 2 MB
    u16* Wkv_t = (u16*)(ws + (4u << 20));    // 256 KB
    u16* xn    = (u16*)(ws + 4456448u);      // 8 MB
    u16* xb    = (u16*)(ws + 12845056u);     // 8 MB (free after kv-gemm; reused for kpart)
    u16* qb    = (u16*)(ws + 21233664u);     // 8 MB
    u16* kb    = (u16*)(ws + 29622272u);     // 512 KB
    u16* vtb   = (u16*)(ws + 30146560u);     // 512 KB
    u16* attb  = (u16*)(ws + 30670848u);     // 8 MB
    float* kpart = (float*)xb;               // 64 floats, written after xb's last use

    const float qscale = 0.125f * 1.44269504f;   // SCALE * log2(e) folded into Wq
    transpose_cast_all<<<dim3(32, 68), dim3(32, 8), 0, stream>>>(Wq, Wkv, Wo, Wq_t, Wkv_t, Wo_t, qscale);

    ln_cast<<<4096, 256, 0, stream>>>(x, gamma, xn, xb);

    gemm_bt<128, 64, 0><<<dim3(32, 16), 256, 0, stream>>>(xn, Wq_t, qb, nullptr, nullptr, 4096, 1024, 1024);
    gemm_bt<64, 64, 2><<<dim3(64, 2), 256, 0, stream>>>(xb, Wkv_t, kb, nullptr, vtb, 4096, 128, 1024);
    kmax_kernel<<<64, 256, 0, stream>>>(kb, kpart);
    attn_fwd<<<512, 256, 0, stream>>>(qb, kb, vtb, kpart, attb);
    gemm_bt<128, 64, 1><<<dim3(32, 16), 256, 0, stream>>>(attb, Wo_t, nullptr, out, nullptr, 4096, 1024, 1024);
}